// Round 4
// baseline (4648.231 us; speedup 1.0000x reference)
//
#include <hip/hip_runtime.h>
#include <math.h>

#define NN 50000
#define TT 4
#define RR 3
#define EE 500000

// ---------------- diagnostic fill (reports ws_size via absmax) ----------------

__global__ __launch_bounds__(256)
void diag_kernel(float* __restrict__ out, float v)
{
    int i = blockIdx.x * 256 + threadIdx.x;
    if (i < NN) out[i] = v;
}

// ---------------- CSR build (per t: R graphs) ----------------

__global__ __launch_bounds__(256)
void count_kernel(const int* __restrict__ dst, int* __restrict__ cnt)
{
    int g = blockIdx.y;
    int e = blockIdx.x * 256 + threadIdx.x;
    if (e >= EE) return;
    int d = dst[(size_t)g * EE + e];
    atomicAdd(&cnt[(size_t)g * NN + d], 1);
}

__global__ __launch_bounds__(256)
void scan_kernel(int* __restrict__ cnt,   // (R,N) counts in, cursor-start out
                 int* __restrict__ rows)  // (R,N+1)
{
    int g = blockIdx.x;
    int tid = threadIdx.x;
    const int CH = (NN + 255) / 256;
    int s0 = tid * CH;
    int s1 = s0 + CH; if (s1 > NN) s1 = NN;
    int* c = cnt + (size_t)g * NN;
    int* ro = rows + (size_t)g * (NN + 1);
    int sum = 0;
    for (int i = s0; i < s1; ++i) sum += c[i];
    __shared__ int sd[256];
    sd[tid] = sum;
    __syncthreads();
    for (int off = 1; off < 256; off <<= 1) {
        int v = 0;
        if (tid >= off) v = sd[tid - off];
        __syncthreads();
        sd[tid] += v;
        __syncthreads();
    }
    int total = sd[255];
    int prefix = (tid == 0) ? 0 : sd[tid - 1];
    for (int i = s0; i < s1; ++i) {
        int cv = c[i];
        ro[i] = prefix;
        c[i] = prefix;   // cursor init
        prefix += cv;
    }
    if (tid == 0) ro[NN] = total;
}

__global__ __launch_bounds__(256)
void fill_kernel(const int* __restrict__ src, const int* __restrict__ dst,
                 const float* __restrict__ ew, int* __restrict__ cur,
                 int2* __restrict__ srcw)
{
    int g = blockIdx.y;
    int e = blockIdx.x * 256 + threadIdx.x;
    if (e >= EE) return;
    size_t idx = (size_t)g * EE + e;
    int d = dst[idx];
    int pos = atomicAdd(&cur[(size_t)g * NN + d], 1);
    int2 p;
    p.x = src[idx];
    p.y = __float_as_int(ew[idx]);
    srcw[(size_t)g * EE + pos] = p;
}

// ---------------- conv gather-aggregate (one wave per (r,n)) ----------------

__global__ __launch_bounds__(256)
void agg_kernel(const float* __restrict__ x,    // (N,128)
                const int2* __restrict__ srcw,  // (R,E)
                const int* __restrict__ rows,   // (R,N+1)
                float* __restrict__ agg)        // (R,N,128)
{
    int wid = (blockIdx.x * 256 + threadIdx.x) >> 6;
    int lane = threadIdx.x & 63;
    if (wid >= RR * NN) return;
    int r = wid / NN;
    int n = wid - r * NN;
    const int* rs = rows + (size_t)r * (NN + 1);
    int e0 = rs[n], e1 = rs[n + 1];
    const int2* sw = srcw + (size_t)r * EE;
    float ax = 0.f, ay = 0.f;
    for (int e = e0; e < e1; ++e) {
        int2 p = sw[e];
        float w = __int_as_float(p.y);
        float2 xr = *(const float2*)(x + (size_t)p.x * 128 + lane * 2);
        ax += w * xr.x;
        ay += w * xr.y;
    }
    float inv = 1.0f / fmaxf((float)(e1 - e0), 1.0f);
    float2 o; o.x = ax * inv; o.y = ay * inv;
    *(float2*)(agg + ((size_t)r * NN + n) * 128 + lane * 2) = o;
}

// ---------------- generic row matmul: out = act(in @ W + b) ----------------
// K = kdiv*128; blockIdx.y = 128-col group of W/out; blockIdx.z = slice.
// In-place safe (rows staged to LDS before any write). NOTE: `in`/`out` may
// alias, so they are NOT __restrict__.

__global__ __launch_bounds__(256)
void mm128(const float* in, long in_zs, int ldin,
           const float* __restrict__ W, long w_zs, int ldw,
           const float* __restrict__ bias, long b_zs,
           float* out, long out_zs, int ldout,
           int rows, int kdiv, int act)
{
    __shared__ float lds[64 * 128];
    const int z = blockIdx.z;
    in += (long)z * in_zs;
    W += (long)z * w_zs + blockIdx.y * 128;
    bias += (long)z * b_zs + blockIdx.y * 128;
    out += (long)z * out_zs + blockIdx.y * 128;
    const int row0 = blockIdx.x * 64;
    const int tid = threadIdx.x;
    const int tx = tid & 31;
    const int ty = tid >> 5;
    float acc[8][4];
#pragma unroll
    for (int i = 0; i < 8; ++i) { acc[i][0] = 0.f; acc[i][1] = 0.f; acc[i][2] = 0.f; acc[i][3] = 0.f; }
    for (int kc = 0; kc < kdiv; ++kc) {
        __syncthreads();
        {
            const int col4 = tx * 4;
#pragma unroll
            for (int p = 0; p < 8; ++p) {
                const int rloc = p * 8 + ty;
                const int grow = row0 + rloc;
                float4 v = make_float4(0.f, 0.f, 0.f, 0.f);
                if (grow < rows) v = *(const float4*)(in + (long)grow * ldin + kc * 128 + col4);
                *(float4*)(&lds[rloc * 128 + col4]) = v;
            }
        }
        __syncthreads();
        const float* Wk = W + (long)kc * 128 * ldw;
        for (int k4 = 0; k4 < 128; k4 += 4) {
            const float4 w0 = *(const float4*)(Wk + (long)(k4 + 0) * ldw + tx * 4);
            const float4 w1 = *(const float4*)(Wk + (long)(k4 + 1) * ldw + tx * 4);
            const float4 w2 = *(const float4*)(Wk + (long)(k4 + 2) * ldw + tx * 4);
            const float4 w3 = *(const float4*)(Wk + (long)(k4 + 3) * ldw + tx * 4);
#pragma unroll
            for (int i = 0; i < 8; ++i) {
                const float4 xv = *(const float4*)(&lds[(ty * 8 + i) * 128 + k4]);
                acc[i][0] += xv.x * w0.x + xv.y * w1.x + xv.z * w2.x + xv.w * w3.x;
                acc[i][1] += xv.x * w0.y + xv.y * w1.y + xv.z * w2.y + xv.w * w3.y;
                acc[i][2] += xv.x * w0.z + xv.y * w1.z + xv.z * w2.z + xv.w * w3.z;
                acc[i][3] += xv.x * w0.w + xv.y * w1.w + xv.z * w2.w + xv.w * w3.w;
            }
        }
    }
    const float4 bv = *(const float4*)(bias + tx * 4);
#pragma unroll
    for (int i = 0; i < 8; ++i) {
        const int grow = row0 + ty * 8 + i;
        if (grow >= rows) continue;
        float4 o;
        o.x = acc[i][0] + bv.x;
        o.y = acc[i][1] + bv.y;
        o.z = acc[i][2] + bv.z;
        o.w = acc[i][3] + bv.w;
        if (act) { o.x = fmaxf(o.x, 0.f); o.y = fmaxf(o.y, 0.f); o.z = fmaxf(o.z, 0.f); o.w = fmaxf(o.w, 0.f); }
        *(float4*)(out + (long)grow * ldout + tx * 4) = o;
    }
}

// ---------------- fused rel-attn + relu + residual + LayerNorm ----------------

__device__ inline float wred(float v)
{
#pragma unroll
    for (int m = 32; m; m >>= 1) v += __shfl_xor(v, m);
    return v;
}

__global__ __launch_bounds__(256)
void attnln_kernel(const float* __restrict__ agg,  // (R,N,128)
                   const float* hin,               // (N,128), may alias hout
                   const float* __restrict__ q,
                   const float* __restrict__ g,
                   const float* __restrict__ b,
                   float* hout)
{
    int wid = (blockIdx.x * 256 + threadIdx.x) >> 6;
    int lane = threadIdx.x & 63;
    if (wid >= NN) return;
    int n = wid;
    float2 qv = *(const float2*)(q + lane * 2);
    float2 s[3];
    float sc[3];
#pragma unroll
    for (int r = 0; r < 3; ++r) {
        s[r] = *(const float2*)(agg + ((size_t)r * NN + n) * 128 + lane * 2);
        sc[r] = wred(tanhf(s[r].x) * qv.x + tanhf(s[r].y) * qv.y);
    }
    float mx = fmaxf(sc[0], fmaxf(sc[1], sc[2]));
    float e0 = __expf(sc[0] - mx), e1 = __expf(sc[1] - mx), e2 = __expf(sc[2] - mx);
    float isum = 1.f / (e0 + e1 + e2);
    float ax = (e0 * s[0].x + e1 * s[1].x + e2 * s[2].x) * isum;
    float ay = (e0 * s[0].y + e1 * s[1].y + e2 * s[2].y) * isum;
    float2 h = *(const float2*)(hin + (size_t)n * 128 + lane * 2);
    float ux = h.x + fmaxf(ax, 0.f);
    float uy = h.y + fmaxf(ay, 0.f);
    float mean = wred(ux + uy) * (1.f / 128.f);
    float dx = ux - mean, dy = uy - mean;
    float var = wred(dx * dx + dy * dy) * (1.f / 128.f);
    float rstd = rsqrtf(var + 1e-5f);
    float2 gv = *(const float2*)(g + lane * 2);
    float2 bv = *(const float2*)(b + lane * 2);
    float2 o;
    o.x = dx * rstd * gv.x + bv.x;
    o.y = dy * rstd * gv.y + bv.y;
    *(float2*)(hout + (size_t)n * 128 + lane * 2) = o;
}

// ---------------- fused GRU pass: one gate group of gi AND gh + epilogue ------
// mode 0: S1 = sigmoid(gi_r + gh_r);  mode 1: S2 = sigmoid(gi_z + gh_z)
// mode 2: n = tanh(gi_n + S1*gh_n); hnew = (1-S2)*n + S2*h -> h, outs
// outs may alias x (block rewrites only rows it staged to LDS) -> no restrict.

__global__ __launch_bounds__(256)
void gru_mm(const float* x,                // (N,128) hs[t]
            float* h,                      // (N,128) running state
            const float* __restrict__ Wi,  // (128,384)
            const float* __restrict__ bi,  // (384)
            const float* __restrict__ Wh,  // (128,384)
            const float* __restrict__ bh,  // (384)
            float* __restrict__ S1,        // (N,128)
            float* __restrict__ S2,        // (N,128)
            float* outs,                   // (N,128) outs[t]
            int mode)
{
    __shared__ float lx[64 * 128];
    __shared__ float lh[64 * 128];
    const int row0 = blockIdx.x * 64;
    const int tid = threadIdx.x;
    const int tx = tid & 31;
    const int ty = tid >> 5;
    {
        const int col4 = tx * 4;
#pragma unroll
        for (int p = 0; p < 8; ++p) {
            const int rl = p * 8 + ty;
            const int gr = row0 + rl;
            float4 vx = make_float4(0.f, 0.f, 0.f, 0.f);
            float4 vh = make_float4(0.f, 0.f, 0.f, 0.f);
            if (gr < NN) {
                vx = *(const float4*)(x + (size_t)gr * 128 + col4);
                vh = *(const float4*)(h + (size_t)gr * 128 + col4);
            }
            *(float4*)(&lx[rl * 128 + col4]) = vx;
            *(float4*)(&lh[rl * 128 + col4]) = vh;
        }
    }
    __syncthreads();
    float ai[8][4], ah[8][4];
#pragma unroll
    for (int i = 0; i < 8; ++i)
#pragma unroll
        for (int j = 0; j < 4; ++j) { ai[i][j] = 0.f; ah[i][j] = 0.f; }
    const float* Wic = Wi + mode * 128;
    const float* Whc = Wh + mode * 128;
    for (int k4 = 0; k4 < 128; k4 += 4) {
        const float4 wi0 = *(const float4*)(Wic + (size_t)(k4 + 0) * 384 + tx * 4);
        const float4 wi1 = *(const float4*)(Wic + (size_t)(k4 + 1) * 384 + tx * 4);
        const float4 wi2 = *(const float4*)(Wic + (size_t)(k4 + 2) * 384 + tx * 4);
        const float4 wi3 = *(const float4*)(Wic + (size_t)(k4 + 3) * 384 + tx * 4);
        const float4 wh0 = *(const float4*)(Whc + (size_t)(k4 + 0) * 384 + tx * 4);
        const float4 wh1 = *(const float4*)(Whc + (size_t)(k4 + 1) * 384 + tx * 4);
        const float4 wh2 = *(const float4*)(Whc + (size_t)(k4 + 2) * 384 + tx * 4);
        const float4 wh3 = *(const float4*)(Whc + (size_t)(k4 + 3) * 384 + tx * 4);
#pragma unroll
        for (int i = 0; i < 8; ++i) {
            const float4 xv = *(const float4*)(&lx[(ty * 8 + i) * 128 + k4]);
            const float4 hv = *(const float4*)(&lh[(ty * 8 + i) * 128 + k4]);
            ai[i][0] += xv.x * wi0.x + xv.y * wi1.x + xv.z * wi2.x + xv.w * wi3.x;
            ai[i][1] += xv.x * wi0.y + xv.y * wi1.y + xv.z * wi2.y + xv.w * wi3.y;
            ai[i][2] += xv.x * wi0.z + xv.y * wi1.z + xv.z * wi2.z + xv.w * wi3.z;
            ai[i][3] += xv.x * wi0.w + xv.y * wi1.w + xv.z * wi2.w + xv.w * wi3.w;
            ah[i][0] += hv.x * wh0.x + hv.y * wh1.x + hv.z * wh2.x + hv.w * wh3.x;
            ah[i][1] += hv.x * wh0.y + hv.y * wh1.y + hv.z * wh2.y + hv.w * wh3.y;
            ah[i][2] += hv.x * wh0.z + hv.y * wh1.z + hv.z * wh2.z + hv.w * wh3.z;
            ah[i][3] += hv.x * wh0.w + hv.y * wh1.w + hv.z * wh2.w + hv.w * wh3.w;
        }
    }
    const float4 biv = *(const float4*)(bi + mode * 128 + tx * 4);
    const float4 bhv = *(const float4*)(bh + mode * 128 + tx * 4);
#pragma unroll
    for (int i = 0; i < 8; ++i) {
        const int gr = row0 + ty * 8 + i;
        if (gr >= NN) continue;
        float gi[4], gh[4];
        gi[0] = ai[i][0] + biv.x; gi[1] = ai[i][1] + biv.y; gi[2] = ai[i][2] + biv.z; gi[3] = ai[i][3] + biv.w;
        gh[0] = ah[i][0] + bhv.x; gh[1] = ah[i][1] + bhv.y; gh[2] = ah[i][2] + bhv.z; gh[3] = ah[i][3] + bhv.w;
        if (mode < 2) {
            float4 o;
            o.x = 1.f / (1.f + __expf(-(gi[0] + gh[0])));
            o.y = 1.f / (1.f + __expf(-(gi[1] + gh[1])));
            o.z = 1.f / (1.f + __expf(-(gi[2] + gh[2])));
            o.w = 1.f / (1.f + __expf(-(gi[3] + gh[3])));
            float* dstp = (mode == 0 ? S1 : S2) + (size_t)gr * 128 + tx * 4;
            *(float4*)dstp = o;
        } else {
            const float4 r4 = *(const float4*)(S1 + (size_t)gr * 128 + tx * 4);
            const float4 z4 = *(const float4*)(S2 + (size_t)gr * 128 + tx * 4);
            const float4 hv4 = *(const float4*)(&lh[(ty * 8 + i) * 128 + tx * 4]);
            float nn0 = tanhf(gi[0] + r4.x * gh[0]);
            float nn1 = tanhf(gi[1] + r4.y * gh[1]);
            float nn2 = tanhf(gi[2] + r4.z * gh[2]);
            float nn3 = tanhf(gi[3] + r4.w * gh[3]);
            float4 o;
            o.x = (1.f - z4.x) * nn0 + z4.x * hv4.x;
            o.y = (1.f - z4.y) * nn1 + z4.y * hv4.y;
            o.z = (1.f - z4.z) * nn2 + z4.z * hv4.z;
            o.w = (1.f - z4.w) * nn3 + z4.w * hv4.w;
            *(float4*)(h + (size_t)gr * 128 + tx * 4) = o;
            *(float4*)(outs + (size_t)gr * 128 + tx * 4) = o;
        }
    }
}

// ---------------- temporal attention (also emits `last`) ----------------

__global__ __launch_bounds__(256)
void temporal_kernel(const float* __restrict__ outs, // (T,N,128)
                     const float* __restrict__ tq,
                     float* __restrict__ zbuf)       // (N,384): 0:128 last, 128:256 attn
{
    int wid = (blockIdx.x * 256 + threadIdx.x) >> 6;
    int lane = threadIdx.x & 63;
    if (wid >= NN) return;
    int n = wid;
    float2 qv = *(const float2*)(tq + lane * 2);
    float2 o[4];
    float sc[4];
#pragma unroll
    for (int t = 0; t < 4; ++t) {
        o[t] = *(const float2*)(outs + ((size_t)t * NN + n) * 128 + lane * 2);
        sc[t] = wred(tanhf(o[t].x) * qv.x + tanhf(o[t].y) * qv.y);
    }
    float mx = fmaxf(fmaxf(sc[0], sc[1]), fmaxf(sc[2], sc[3]));
    float e[4];
    float sum = 0.f;
#pragma unroll
    for (int t = 0; t < 4; ++t) { e[t] = __expf(sc[t] - mx); sum += e[t]; }
    float isum = 1.f / sum;
    float ax = 0.f, ay = 0.f;
#pragma unroll
    for (int t = 0; t < 4; ++t) { ax += e[t] * o[t].x; ay += e[t] * o[t].y; }
    ax *= isum; ay *= isum;
    float* zr = zbuf + (size_t)n * 384;
    *(float2*)(zr + lane * 2) = o[3];
    float2 at; at.x = ax; at.y = ay;
    *(float2*)(zr + 128 + lane * 2) = at;
}

// ---------------- final dot: out[n] = hid[n] . cW2 + cb2 ----------------

__global__ __launch_bounds__(256)
void dot_kernel(const float* __restrict__ hid, const float* __restrict__ cW2,
                const float* __restrict__ cb2, float* __restrict__ outv)
{
    int wid = (blockIdx.x * 256 + threadIdx.x) >> 6;
    int lane = threadIdx.x & 63;
    if (wid >= NN) return;
    float2 hv = *(const float2*)(hid + (size_t)wid * 128 + lane * 2);
    float2 wv = *(const float2*)(cW2 + lane * 2);
    float v = wred(hv.x * wv.x + hv.y * wv.y);
    if (lane == 0) outv[wid] = v + cb2[0];
}

// ---------------- launch ----------------

extern "C" void kernel_launch(void* const* d_in, const int* in_sizes, int n_in,
                              void* d_out, int out_size, void* d_ws, size_t ws_size,
                              hipStream_t stream)
{
    const float* feat = (const float*)d_in[0];
    const int* srcp   = (const int*)d_in[1];
    const int* dstp   = (const int*)d_in[2];
    const float* ewp  = (const float*)d_in[3];
    const float* W_in = (const float*)d_in[4];
    const float* b_in = (const float*)d_in[5];
    const float* W1   = (const float*)d_in[6];
    const float* b1   = (const float*)d_in[7];
    const float* W2   = (const float*)d_in[8];
    const float* b2   = (const float*)d_in[9];
    const float* q1   = (const float*)d_in[10];
    const float* q2   = (const float*)d_in[11];
    const float* ln1g = (const float*)d_in[12];
    const float* ln1b = (const float*)d_in[13];
    const float* ln2g = (const float*)d_in[14];
    const float* ln2b = (const float*)d_in[15];
    const float* gWih = (const float*)d_in[16];
    const float* gbih = (const float*)d_in[17];
    const float* gWhh = (const float*)d_in[18];
    const float* gbhh = (const float*)d_in[19];
    const float* tq   = (const float*)d_in[20];
    const float* tW1  = (const float*)d_in[21];
    const float* tb1  = (const float*)d_in[22];
    const float* tW2  = (const float*)d_in[23];
    const float* tb2  = (const float*)d_in[24];
    const float* cW1  = (const float*)d_in[25];
    const float* cb1  = (const float*)d_in[26];
    const float* cW2  = (const float*)d_in[27];
    const float* cb2  = (const float*)d_in[28];
    float* outv = (float*)d_out;
    (void)in_sizes; (void)n_in; (void)out_size;

    // ---- manual ws layout (bytes), peak ~218 MB ----
    const size_t o_OUTS = 0;                          // (T,N,128) f32 = 102,400,000
    const size_t o_POOL = 102400000;                  // overlay pool
    const size_t o_AGG  = o_POOL;                     // (R,N,128) 76.8M | S1/S2 | Zbuf(N,384)
    const size_t o_S1   = o_POOL;
    const size_t o_S2   = o_POOL + 25600000;
    const size_t o_H    = o_POOL + 76800000;          // (N,128) 25.6M | HST | TABH
    const size_t o_SRCW = o_H + 25600000;             // (R,E) int2 = 12M
    const size_t o_ROWS = o_SRCW + 12000000;          // (R,N+1) int = 600,012 -> pad
    const size_t o_CURS = o_ROWS + 600064;            // (R,N) int = 600,000
    const size_t NEED   = o_CURS + 600064;

    if (ws_size < NEED) {
        // clean failure that reports the actual budget: absmax ~= ws_size in MB
        diag_kernel<<<dim3((NN + 255) / 256), dim3(256), 0, stream>>>(outv, (float)(ws_size >> 20));
        return;
    }

    char* wsb = (char*)d_ws;
    float* HS   = (float*)(wsb + o_OUTS);  // h2 per t, then GRU outs (aliased)
    float* AGG  = (float*)(wsb + o_AGG);
    float* S1   = (float*)(wsb + o_S1);
    float* S2   = (float*)(wsb + o_S2);
    float* H    = (float*)(wsb + o_H);     // per-t h0/h1 scratch
    float* HST  = (float*)(wsb + o_H);     // GRU hidden state (reuses H region)
    float* TABH = (float*)(wsb + o_H);     // classifier scratch (reuses again)
    float* ZB   = (float*)(wsb + o_AGG);   // (N,384) concat buffer
    int2*  SRCW = (int2*)(wsb + o_SRCW);
    int*   ROWS = (int*)(wsb + o_ROWS);
    int*   CURS = (int*)(wsb + o_CURS);

    const dim3 blk(256);
    const int G64 = (NN + 63) / 64;     // 782
    const dim3 gE((EE + 255) / 256, RR);

    // ---------- phase A: spatial layers, t-outer ----------
    for (int t = 0; t < TT; ++t) {
        const size_t eoff = (size_t)t * RR * EE;
        // CSR for graph t
        hipMemsetAsync(CURS, 0, (size_t)RR * NN * 4, stream);
        count_kernel<<<gE, blk, 0, stream>>>(dstp + eoff, CURS);
        scan_kernel<<<dim3(RR), blk, 0, stream>>>(CURS, ROWS);
        fill_kernel<<<gE, blk, 0, stream>>>(srcp + eoff, dstp + eoff, ewp + eoff, CURS, SRCW);

        // h0 = relu(feat[t] @ W_in + b_in) -> H
        mm128<<<dim3(G64, 1, 1), blk, 0, stream>>>(
            feat + (size_t)t * NN * 128, 0, 128, W_in, 0, 128, b_in, 0, H, 0, 128, NN, 1, 1);

        for (int layer = 0; layer < 2; ++layer) {
            const float* Wl = layer ? W2 : W1;
            const float* bl = layer ? b2 : b1;
            const float* ql = layer ? q2 : q1;
            const float* lg = layer ? ln2g : ln1g;
            const float* lb = layer ? ln2b : ln1b;
            float* hout = layer ? (HS + (size_t)t * NN * 128) : H;
            agg_kernel<<<dim3((RR * NN) / 4), blk, 0, stream>>>(H, SRCW, ROWS, AGG);
            mm128<<<dim3(G64, 1, RR), blk, 0, stream>>>(
                AGG, (long)NN * 128, 128, Wl, 128 * 128, 128, bl, 128,
                AGG, (long)NN * 128, 128, NN, 1, 0);
            attnln_kernel<<<dim3(NN / 4), blk, 0, stream>>>(AGG, H, ql, lg, lb, hout);
        }
    }

    // ---------- phase B: GRU over T (outs alias HS) ----------
    hipMemsetAsync(HST, 0, (size_t)NN * 128 * 4, stream);
    for (int t = 0; t < TT; ++t) {
        float* xt = HS + (size_t)t * NN * 128;
        for (int mode = 0; mode < 3; ++mode)
            gru_mm<<<dim3(G64), blk, 0, stream>>>(
                xt, HST, gWih, gbih, gWhh, gbhh, S1, S2, xt, mode);
    }

    // ---------- phase C: temporal attn + tab + classifier ----------
    temporal_kernel<<<dim3(NN / 4), blk, 0, stream>>>(HS, tq, ZB);

    mm128<<<dim3(G64, 1, 1), blk, 0, stream>>>(
        feat + (size_t)3 * NN * 128, 0, 128, tW1, 0, 128, tb1, 0, TABH, 0, 128, NN, 1, 1);
    mm128<<<dim3(G64, 1, 1), blk, 0, stream>>>(
        TABH, 0, 128, tW2, 0, 128, tb2, 0, ZB + 256, 0, 384, NN, 1, 1);

    mm128<<<dim3(G64, 1, 1), blk, 0, stream>>>(
        ZB, 0, 384, cW1, 0, 128, cb1, 0, TABH, 0, 128, NN, 3, 1);

    dot_kernel<<<dim3(NN / 4), blk, 0, stream>>>(TABH, cW2, cb2, outv);
}

// Round 5
// 3292.713 us; speedup vs baseline: 1.4117x; 1.4117x over previous
//
#include <hip/hip_runtime.h>
#include <hip/hip_bf16.h>
#include <math.h>

#define NN 50000
#define TT 4
#define RR 3
#define EE 500000

typedef __attribute__((ext_vector_type(8))) short bf16x8;
typedef __attribute__((ext_vector_type(4))) float f32x4;

__device__ inline unsigned short f2b(float f)
{
    union { __hip_bfloat16 h; unsigned short u; } cv;
    cv.h = __float2bfloat16(f);
    return cv.u;
}
__device__ inline float b2f(unsigned short u)
{
    union { unsigned int u; float f; } cv;
    cv.u = ((unsigned int)u) << 16;
    return cv.f;
}
__device__ inline bf16x8 pack8(float4 a, float4 b)
{
    bf16x8 r;
    r[0] = (short)f2b(a.x); r[1] = (short)f2b(a.y); r[2] = (short)f2b(a.z); r[3] = (short)f2b(a.w);
    r[4] = (short)f2b(b.x); r[5] = (short)f2b(b.y); r[6] = (short)f2b(b.z); r[7] = (short)f2b(b.w);
    return r;
}

// ---------------- diagnostic fill (reports ws_size via absmax) ----------------

__global__ __launch_bounds__(256)
void diag_kernel(float* __restrict__ out, float v)
{
    int i = blockIdx.x * 256 + threadIdx.x;
    if (i < NN) out[i] = v;
}

// ---------------- weight swizzle: (S,128,C) fp32 -> MFMA B-frag bf16 ----------
// dst[((s*4+kc)*ncg + cg)*64*8 + lane*8 + j] = bf16(W[s][kc*32+(lane>>4)*8+j][cg*16+(lane&15)])

__global__ __launch_bounds__(256)
void wswz_kernel(const float* __restrict__ W, unsigned short* __restrict__ dst, int C, int S)
{
    int idx = blockIdx.x * 256 + threadIdx.x;
    int per = 128 * C;
    if (idx >= S * per) return;
    int s = idx / per, rem = idx - s * per;
    int j = rem & 7;
    int lane = (rem >> 3) & 63;
    int blk = rem >> 9;
    int ncg = C >> 4;
    int kc = blk / ncg, cg = blk - kc * ncg;
    int k = kc * 32 + (lane >> 4) * 8 + j;
    int c = cg * 16 + (lane & 15);
    dst[idx] = f2b(W[(size_t)s * 128 * C + (size_t)k * C + c]);
}

// ---------------- CSR build (per t: R graphs) ----------------

__global__ __launch_bounds__(256)
void count_kernel(const int* __restrict__ dst, int* __restrict__ cnt)
{
    int g = blockIdx.y;
    int e = blockIdx.x * 256 + threadIdx.x;
    if (e >= EE) return;
    int d = dst[(size_t)g * EE + e];
    atomicAdd(&cnt[(size_t)g * NN + d], 1);
}

__global__ __launch_bounds__(256)
void scan_kernel(int* __restrict__ cnt, int* __restrict__ rows)
{
    int g = blockIdx.x;
    int tid = threadIdx.x;
    const int CH = (NN + 255) / 256;
    int s0 = tid * CH;
    int s1 = s0 + CH; if (s1 > NN) s1 = NN;
    int* c = cnt + (size_t)g * NN;
    int* ro = rows + (size_t)g * (NN + 1);
    int sum = 0;
    for (int i = s0; i < s1; ++i) sum += c[i];
    __shared__ int sd[256];
    sd[tid] = sum;
    __syncthreads();
    for (int off = 1; off < 256; off <<= 1) {
        int v = 0;
        if (tid >= off) v = sd[tid - off];
        __syncthreads();
        sd[tid] += v;
        __syncthreads();
    }
    int total = sd[255];
    int prefix = (tid == 0) ? 0 : sd[tid - 1];
    for (int i = s0; i < s1; ++i) {
        int cv = c[i];
        ro[i] = prefix;
        c[i] = prefix;
        prefix += cv;
    }
    if (tid == 0) ro[NN] = total;
}

__global__ __launch_bounds__(256)
void fill_kernel(const int* __restrict__ src, const int* __restrict__ dst,
                 const float* __restrict__ ew, int* __restrict__ cur,
                 int2* __restrict__ srcw)
{
    int g = blockIdx.y;
    int e = blockIdx.x * 256 + threadIdx.x;
    if (e >= EE) return;
    size_t idx = (size_t)g * EE + e;
    int d = dst[idx];
    int pos = atomicAdd(&cur[(size_t)g * NN + d], 1);
    int2 p;
    p.x = src[idx];
    p.y = __float_as_int(ew[idx]);
    srcw[(size_t)g * EE + pos] = p;
}

// ---------------- conv gather-aggregate over bf16 rows ----------------

__global__ __launch_bounds__(256)
void agg16_kernel(const unsigned short* __restrict__ x16,  // (N,128) bf16
                  const int2* __restrict__ srcw,           // (R,E)
                  const int* __restrict__ rows,            // (R,N+1)
                  unsigned short* __restrict__ agg16)      // (R,N,128) bf16
{
    int wid = (blockIdx.x * 256 + threadIdx.x) >> 6;
    int lane = threadIdx.x & 63;
    if (wid >= RR * NN) return;
    int r = wid / NN;
    int n = wid - r * NN;
    const int* rs = rows + (size_t)r * (NN + 1);
    int e0 = rs[n], e1 = rs[n + 1];
    const int2* sw = srcw + (size_t)r * EE;
    float ax = 0.f, ay = 0.f;
    for (int e = e0; e < e1; ++e) {
        int2 p = sw[e];
        float w = __int_as_float(p.y);
        unsigned int v = *(const unsigned int*)(x16 + (size_t)p.x * 128 + lane * 2);
        ax += w * b2f((unsigned short)(v & 0xffffu));
        ay += w * b2f((unsigned short)(v >> 16));
    }
    float inv = 1.0f / fmaxf((float)(e1 - e0), 1.0f);
    unsigned int o = (unsigned int)f2b(ax * inv) | ((unsigned int)f2b(ay * inv) << 16);
    *(unsigned int*)(agg16 + ((size_t)r * NN + n) * 128 + lane * 2) = o;
}

// ---------------- MFMA matmul: out = act(in @ W + b), K=128, 128 cols --------
// in: fp32 (in_bf16=0) or bf16 (in_bf16=1), ld ldin. Ws: swizzled bf16 frags.
// out (fp32, ld ldout) and/or out16 (bf16, ld 128) optional.
// In-place safe for in==out16 (wave loads all its A-frags before any store).

__global__ __launch_bounds__(256)
void mmb(const void* in, int in_bf16, long in_zs, int ldin,
         const unsigned short* __restrict__ Ws, long w_zs,
         const float* __restrict__ bias, long b_zs,
         float* out, long out_zs, int ldout,
         unsigned short* out16, long out16_zs,
         int rows, int act)
{
    const int tid = threadIdx.x;
    const int wv = tid >> 6, l = tid & 63;
    const int z = blockIdx.z;
    const int r0 = blockIdx.x * 64 + wv * 16;
    const int lk = (l >> 4) * 8;
    int rowA = r0 + (l & 15);
    int rowc = rowA < rows ? rowA : rows - 1;

    bf16x8 a[4];
    if (in_bf16) {
        const unsigned short* inb = (const unsigned short*)in + (size_t)z * in_zs
                                    + (size_t)rowc * ldin + lk;
#pragma unroll
        for (int kc = 0; kc < 4; ++kc) {
            uint4 u = *(const uint4*)(inb + kc * 32);
            a[kc] = *(bf16x8*)&u;
        }
    } else {
        const float* inf = (const float*)in + (size_t)z * in_zs
                           + (size_t)rowc * ldin + lk;
#pragma unroll
        for (int kc = 0; kc < 4; ++kc) {
            float4 u0 = *(const float4*)(inf + kc * 32);
            float4 u1 = *(const float4*)(inf + kc * 32 + 4);
            a[kc] = pack8(u0, u1);
        }
    }

    const unsigned short* Wz = Ws + (size_t)z * w_zs;
    const float* bz = bias + (size_t)z * b_zs;
    float* oz = out ? out + (size_t)z * out_zs : (float*)0;
    unsigned short* o16z = out16 ? out16 + (size_t)z * out16_zs : (unsigned short*)0;
    const int colbase = l & 15;
    const int rbase = r0 + (l >> 4) * 4;

#pragma unroll
    for (int cg = 0; cg < 8; ++cg) {
        f32x4 acc = {0.f, 0.f, 0.f, 0.f};
#pragma unroll
        for (int kc = 0; kc < 4; ++kc) {
            uint4 bu = *(const uint4*)(Wz + ((size_t)(kc * 8 + cg) * 64 + l) * 8);
            acc = __builtin_amdgcn_mfma_f32_16x16x32_bf16(a[kc], *(bf16x8*)&bu, acc, 0, 0, 0);
        }
        int col = cg * 16 + colbase;
        float bvv = bz[col];
#pragma unroll
        for (int j = 0; j < 4; ++j) {
            int gr = rbase + j;
            if (gr >= rows) continue;
            float v = acc[j] + bvv;
            if (act) v = fmaxf(v, 0.f);
            if (oz) oz[(size_t)gr * ldout + col] = v;
            if (o16z) o16z[(size_t)gr * 128 + col] = f2b(v);
        }
    }
}

// ---------------- MFMA GRU pass (one gate group of both gemms + epilogue) ----
// mode 0: S1=sigmoid(gi_r+gh_r); 1: S2=sigmoid(gi_z+gh_z)
// 2: n=tanh(gi_n + S1*gh_n); hnew=(1-S2)*n+S2*h -> h, outs (outs may alias x)

__global__ __launch_bounds__(256)
void grub(const float* x, float* h,
          const unsigned short* __restrict__ Wis, const float* __restrict__ bi,
          const unsigned short* __restrict__ Whs, const float* __restrict__ bh,
          float* __restrict__ S1, float* __restrict__ S2,
          float* outs, int mode)
{
    const int tid = threadIdx.x;
    const int wv = tid >> 6, l = tid & 63;
    const int r0 = blockIdx.x * 64 + wv * 16;
    const int lk = (l >> 4) * 8;
    int rowA = r0 + (l & 15);
    int rowc = rowA < NN ? rowA : NN - 1;

    bf16x8 ax[4], hx[4];
    {
        const float* bx = x + (size_t)rowc * 128 + lk;
        const float* bhp = h + (size_t)rowc * 128 + lk;
#pragma unroll
        for (int kc = 0; kc < 4; ++kc) {
            ax[kc] = pack8(*(const float4*)(bx + kc * 32), *(const float4*)(bx + kc * 32 + 4));
            hx[kc] = pack8(*(const float4*)(bhp + kc * 32), *(const float4*)(bhp + kc * 32 + 4));
        }
    }
    const int colbase = l & 15;
    const int rbase = r0 + (l >> 4) * 4;

#pragma unroll
    for (int cg = 0; cg < 8; ++cg) {
        f32x4 ai = {0.f, 0.f, 0.f, 0.f};
        f32x4 ah = {0.f, 0.f, 0.f, 0.f};
        int cgg = mode * 8 + cg;
#pragma unroll
        for (int kc = 0; kc < 4; ++kc) {
            uint4 bu = *(const uint4*)(Wis + ((size_t)(kc * 24 + cgg) * 64 + l) * 8);
            uint4 bv = *(const uint4*)(Whs + ((size_t)(kc * 24 + cgg) * 64 + l) * 8);
            ai = __builtin_amdgcn_mfma_f32_16x16x32_bf16(ax[kc], *(bf16x8*)&bu, ai, 0, 0, 0);
            ah = __builtin_amdgcn_mfma_f32_16x16x32_bf16(hx[kc], *(bf16x8*)&bv, ah, 0, 0, 0);
        }
        int col = cg * 16 + colbase;
        float biv = bi[mode * 128 + col];
        float bhv = bh[mode * 128 + col];
#pragma unroll
        for (int j = 0; j < 4; ++j) {
            int gr = rbase + j;
            if (gr >= NN) continue;
            float gi = ai[j] + biv;
            float gh = ah[j] + bhv;
            if (mode < 2) {
                float s = 1.f / (1.f + __expf(-(gi + gh)));
                (mode == 0 ? S1 : S2)[(size_t)gr * 128 + col] = s;
            } else {
                float r_ = S1[(size_t)gr * 128 + col];
                float z_ = S2[(size_t)gr * 128 + col];
                float hv = h[(size_t)gr * 128 + col];
                float n_ = tanhf(gi + r_ * gh);
                float o = (1.f - z_) * n_ + z_ * hv;
                h[(size_t)gr * 128 + col] = o;
                outs[(size_t)gr * 128 + col] = o;
            }
        }
    }
}

// ---------------- legacy fp32 matmul (classifier K=384) ----------------

__global__ __launch_bounds__(256)
void mm128(const float* in, long in_zs, int ldin,
           const float* __restrict__ W, long w_zs, int ldw,
           const float* __restrict__ bias, long b_zs,
           float* out, long out_zs, int ldout,
           int rows, int kdiv, int act)
{
    __shared__ float lds[64 * 128];
    const int z = blockIdx.z;
    in += (long)z * in_zs;
    W += (long)z * w_zs + blockIdx.y * 128;
    bias += (long)z * b_zs + blockIdx.y * 128;
    out += (long)z * out_zs + blockIdx.y * 128;
    const int row0 = blockIdx.x * 64;
    const int tid = threadIdx.x;
    const int tx = tid & 31;
    const int ty = tid >> 5;
    float acc[8][4];
#pragma unroll
    for (int i = 0; i < 8; ++i) { acc[i][0] = 0.f; acc[i][1] = 0.f; acc[i][2] = 0.f; acc[i][3] = 0.f; }
    for (int kc = 0; kc < kdiv; ++kc) {
        __syncthreads();
        {
            const int col4 = tx * 4;
#pragma unroll
            for (int p = 0; p < 8; ++p) {
                const int rloc = p * 8 + ty;
                const int grow = row0 + rloc;
                float4 v = make_float4(0.f, 0.f, 0.f, 0.f);
                if (grow < rows) v = *(const float4*)(in + (long)grow * ldin + kc * 128 + col4);
                *(float4*)(&lds[rloc * 128 + col4]) = v;
            }
        }
        __syncthreads();
        const float* Wk = W + (long)kc * 128 * ldw;
        for (int k4 = 0; k4 < 128; k4 += 4) {
            const float4 w0 = *(const float4*)(Wk + (long)(k4 + 0) * ldw + tx * 4);
            const float4 w1 = *(const float4*)(Wk + (long)(k4 + 1) * ldw + tx * 4);
            const float4 w2 = *(const float4*)(Wk + (long)(k4 + 2) * ldw + tx * 4);
            const float4 w3 = *(const float4*)(Wk + (long)(k4 + 3) * ldw + tx * 4);
#pragma unroll
            for (int i = 0; i < 8; ++i) {
                const float4 xv = *(const float4*)(&lds[(ty * 8 + i) * 128 + k4]);
                acc[i][0] += xv.x * w0.x + xv.y * w1.x + xv.z * w2.x + xv.w * w3.x;
                acc[i][1] += xv.x * w0.y + xv.y * w1.y + xv.z * w2.y + xv.w * w3.y;
                acc[i][2] += xv.x * w0.z + xv.y * w1.z + xv.z * w2.z + xv.w * w3.z;
                acc[i][3] += xv.x * w0.w + xv.y * w1.w + xv.z * w2.w + xv.w * w3.w;
            }
        }
    }
    const float4 bv = *(const float4*)(bias + tx * 4);
#pragma unroll
    for (int i = 0; i < 8; ++i) {
        const int grow = row0 + ty * 8 + i;
        if (grow >= rows) continue;
        float4 o;
        o.x = acc[i][0] + bv.x;
        o.y = acc[i][1] + bv.y;
        o.z = acc[i][2] + bv.z;
        o.w = acc[i][3] + bv.w;
        if (act) { o.x = fmaxf(o.x, 0.f); o.y = fmaxf(o.y, 0.f); o.z = fmaxf(o.z, 0.f); o.w = fmaxf(o.w, 0.f); }
        *(float4*)(out + (long)grow * ldout + tx * 4) = o;
    }
}

// ---------------- fused rel-attn + relu + residual + LayerNorm ----------------

__device__ inline float wred(float v)
{
#pragma unroll
    for (int m = 32; m; m >>= 1) v += __shfl_xor(v, m);
    return v;
}

__global__ __launch_bounds__(256)
void attnln_kernel(const unsigned short* __restrict__ agg16, // (R,N,128) bf16 conv outs
                   const float* hin,                          // (N,128), may alias hout
                   const float* __restrict__ q,
                   const float* __restrict__ g,
                   const float* __restrict__ b,
                   float* hout,
                   unsigned short* hout16)                    // optional bf16 mirror
{
    int wid = (blockIdx.x * 256 + threadIdx.x) >> 6;
    int lane = threadIdx.x & 63;
    if (wid >= NN) return;
    int n = wid;
    float2 qv = *(const float2*)(q + lane * 2);
    float sx[3], sy[3], sc[3];
#pragma unroll
    for (int r = 0; r < 3; ++r) {
        unsigned int v = *(const unsigned int*)(agg16 + ((size_t)r * NN + n) * 128 + lane * 2);
        sx[r] = b2f((unsigned short)(v & 0xffffu));
        sy[r] = b2f((unsigned short)(v >> 16));
        sc[r] = wred(tanhf(sx[r]) * qv.x + tanhf(sy[r]) * qv.y);
    }
    float mx = fmaxf(sc[0], fmaxf(sc[1], sc[2]));
    float e0 = __expf(sc[0] - mx), e1 = __expf(sc[1] - mx), e2 = __expf(sc[2] - mx);
    float isum = 1.f / (e0 + e1 + e2);
    float axv = (e0 * sx[0] + e1 * sx[1] + e2 * sx[2]) * isum;
    float ayv = (e0 * sy[0] + e1 * sy[1] + e2 * sy[2]) * isum;
    float2 hv = *(const float2*)(hin + (size_t)n * 128 + lane * 2);
    float ux = hv.x + fmaxf(axv, 0.f);
    float uy = hv.y + fmaxf(ayv, 0.f);
    float mean = wred(ux + uy) * (1.f / 128.f);
    float dx = ux - mean, dy = uy - mean;
    float var = wred(dx * dx + dy * dy) * (1.f / 128.f);
    float rstd = rsqrtf(var + 1e-5f);
    float2 gv = *(const float2*)(g + lane * 2);
    float2 bv = *(const float2*)(b + lane * 2);
    float2 o;
    o.x = dx * rstd * gv.x + bv.x;
    o.y = dy * rstd * gv.y + bv.y;
    *(float2*)(hout + (size_t)n * 128 + lane * 2) = o;
    if (hout16) {
        unsigned int p = (unsigned int)f2b(o.x) | ((unsigned int)f2b(o.y) << 16);
        *(unsigned int*)(hout16 + (size_t)n * 128 + lane * 2) = p;
    }
}

// ---------------- temporal attention (also emits `last`) ----------------

__global__ __launch_bounds__(256)
void temporal_kernel(const float* __restrict__ outs, // (T,N,128)
                     const float* __restrict__ tq,
                     float* __restrict__ zbuf)       // (N,384)
{
    int wid = (blockIdx.x * 256 + threadIdx.x) >> 6;
    int lane = threadIdx.x & 63;
    if (wid >= NN) return;
    int n = wid;
    float2 qv = *(const float2*)(tq + lane * 2);
    float2 o[4];
    float sc[4];
#pragma unroll
    for (int t = 0; t < 4; ++t) {
        o[t] = *(const float2*)(outs + ((size_t)t * NN + n) * 128 + lane * 2);
        sc[t] = wred(tanhf(o[t].x) * qv.x + tanhf(o[t].y) * qv.y);
    }
    float mx = fmaxf(fmaxf(sc[0], sc[1]), fmaxf(sc[2], sc[3]));
    float e[4];
    float sum = 0.f;
#pragma unroll
    for (int t = 0; t < 4; ++t) { e[t] = __expf(sc[t] - mx); sum += e[t]; }
    float isum = 1.f / sum;
    float axv = 0.f, ayv = 0.f;
#pragma unroll
    for (int t = 0; t < 4; ++t) { axv += e[t] * o[t].x; ayv += e[t] * o[t].y; }
    axv *= isum; ayv *= isum;
    float* zr = zbuf + (size_t)n * 384;
    *(float2*)(zr + lane * 2) = o[3];
    float2 at; at.x = axv; at.y = ayv;
    *(float2*)(zr + 128 + lane * 2) = at;
}

// ---------------- final dot ----------------

__global__ __launch_bounds__(256)
void dot_kernel(const float* __restrict__ hid, const float* __restrict__ cW2,
                const float* __restrict__ cb2, float* __restrict__ outv)
{
    int wid = (blockIdx.x * 256 + threadIdx.x) >> 6;
    int lane = threadIdx.x & 63;
    if (wid >= NN) return;
    float2 hv = *(const float2*)(hid + (size_t)wid * 128 + lane * 2);
    float2 wv = *(const float2*)(cW2 + lane * 2);
    float v = wred(hv.x * wv.x + hv.y * wv.y);
    if (lane == 0) outv[wid] = v + cb2[0];
}

// ---------------- launch ----------------

extern "C" void kernel_launch(void* const* d_in, const int* in_sizes, int n_in,
                              void* d_out, int out_size, void* d_ws, size_t ws_size,
                              hipStream_t stream)
{
    const float* feat = (const float*)d_in[0];
    const int* srcp   = (const int*)d_in[1];
    const int* dstp   = (const int*)d_in[2];
    const float* ewp  = (const float*)d_in[3];
    const float* W_in = (const float*)d_in[4];
    const float* b_in = (const float*)d_in[5];
    const float* W1   = (const float*)d_in[6];
    const float* b1   = (const float*)d_in[7];
    const float* W2   = (const float*)d_in[8];
    const float* b2   = (const float*)d_in[9];
    const float* q1   = (const float*)d_in[10];
    const float* q2   = (const float*)d_in[11];
    const float* ln1g = (const float*)d_in[12];
    const float* ln1b = (const float*)d_in[13];
    const float* ln2g = (const float*)d_in[14];
    const float* ln2b = (const float*)d_in[15];
    const float* gWih = (const float*)d_in[16];
    const float* gbih = (const float*)d_in[17];
    const float* gWhh = (const float*)d_in[18];
    const float* gbhh = (const float*)d_in[19];
    const float* tq   = (const float*)d_in[20];
    const float* tW1  = (const float*)d_in[21];
    const float* tb1  = (const float*)d_in[22];
    const float* tW2  = (const float*)d_in[23];
    const float* tb2  = (const float*)d_in[24];
    const float* cW1  = (const float*)d_in[25];
    const float* cb1  = (const float*)d_in[26];
    const float* cW2  = (const float*)d_in[27];
    const float* cb2  = (const float*)d_in[28];
    float* outv = (float*)d_out;
    (void)in_sizes; (void)n_in; (void)out_size;

    // ---- ws layout (bytes), peak ~205.3 MB (round-4 proved >=218 MB OK) ----
    const size_t o_HS    = 0;                      // (T,N,128) fp32 = 102,400,000
    const size_t o_POOL  = 102400000;              // 76.8 MB phase-layered pool
    const size_t o_AGG16 = o_POOL;                 // phase A: (R,N,128) bf16 = 38,400,000
    const size_t o_H16   = o_POOL + 38400000;      // phase A: (N,128) bf16 = 12,800,000
    const size_t o_SRCW  = o_POOL + 51200000;      // phase A: (R,E) int2 = 12,000,000
    const size_t o_ROWS  = o_POOL + 63200000;      // phase A: 600,064
    const size_t o_CURS  = o_POOL + 63800064;      // phase A: 600,064
    const size_t o_S1    = o_POOL;                 // phase B: (N,128) fp32 = 25,600,000
    const size_t o_S2    = o_POOL + 25600000;      // phase B: (N,128) fp32
    const size_t o_ZB    = o_POOL;                 // phase C: (N,384) fp32 = 76,800,000
    const size_t o_H     = o_POOL + 76800000;      // (N,128) fp32 = 25,600,000 (H/HST/TABH)
    const size_t o_WSZ   = o_H + 25600000;         // swizzled bf16 weights, 491,520
    const size_t NEED    = o_WSZ + 491520;

    if (ws_size < NEED) {
        diag_kernel<<<dim3((NN + 255) / 256), dim3(256), 0, stream>>>(outv, (float)(ws_size >> 20));
        return;
    }

    char* wsb = (char*)d_ws;
    float* HS            = (float*)(wsb + o_HS);
    unsigned short* AGG16 = (unsigned short*)(wsb + o_AGG16);
    unsigned short* H16   = (unsigned short*)(wsb + o_H16);
    int2*  SRCW          = (int2*)(wsb + o_SRCW);
    int*   ROWS          = (int*)(wsb + o_ROWS);
    int*   CURS          = (int*)(wsb + o_CURS);
    float* S1            = (float*)(wsb + o_S1);
    float* S2            = (float*)(wsb + o_S2);
    float* ZB            = (float*)(wsb + o_ZB);
    float* H             = (float*)(wsb + o_H);    // h0/h1 scratch
    float* HST           = (float*)(wsb + o_H);    // GRU state (same region)
    float* TABH          = (float*)(wsb + o_H);    // classifier scratch (same region)
    unsigned short* WSZ  = (unsigned short*)(wsb + o_WSZ);

    // swizzled weight sub-offsets (ushort units)
    unsigned short* Wins  = WSZ;            // 16384
    unsigned short* W1s   = WSZ + 16384;    // 49152 (3 slices)
    unsigned short* W2s   = WSZ + 65536;    // 49152
    unsigned short* gWihs = WSZ + 114688;   // 49152 (C=384)
    unsigned short* gWhhs = WSZ + 163840;   // 49152
    unsigned short* tW1s  = WSZ + 212992;   // 16384
    unsigned short* tW2s  = WSZ + 229376;   // 16384

    const dim3 blk(256);
    const int G64 = (NN + 63) / 64;     // 782
    const dim3 gE((EE + 255) / 256, RR);

    // ---------- weight swizzle ----------
    wswz_kernel<<<dim3((1 * 16384 + 255) / 256), blk, 0, stream>>>(W_in, Wins, 128, 1);
    wswz_kernel<<<dim3((3 * 16384 + 255) / 256), blk, 0, stream>>>(W1,   W1s,  128, 3);
    wswz_kernel<<<dim3((3 * 16384 + 255) / 256), blk, 0, stream>>>(W2,   W2s,  128, 3);
    wswz_kernel<<<dim3((1 * 49152 + 255) / 256), blk, 0, stream>>>(gWih, gWihs, 384, 1);
    wswz_kernel<<<dim3((1 * 49152 + 255) / 256), blk, 0, stream>>>(gWhh, gWhhs, 384, 1);
    wswz_kernel<<<dim3((1 * 16384 + 255) / 256), blk, 0, stream>>>(tW1,  tW1s, 128, 1);
    wswz_kernel<<<dim3((1 * 16384 + 255) / 256), blk, 0, stream>>>(tW2,  tW2s, 128, 1);

    // ---------- phase A: spatial layers, t-outer ----------
    for (int t = 0; t < TT; ++t) {
        const size_t eoff = (size_t)t * RR * EE;
        hipMemsetAsync(CURS, 0, (size_t)RR * NN * 4, stream);
        count_kernel<<<gE, blk, 0, stream>>>(dstp + eoff, CURS);
        scan_kernel<<<dim3(RR), blk, 0, stream>>>(CURS, ROWS);
        fill_kernel<<<gE, blk, 0, stream>>>(srcp + eoff, dstp + eoff, ewp + eoff, CURS, SRCW);

        // h0 = relu(feat[t] @ W_in + b_in) -> H (fp32) + H16 (bf16)
        mmb<<<dim3(G64, 1, 1), blk, 0, stream>>>(
            (const void*)(feat + (size_t)t * NN * 128), 0, 0, 128,
            Wins, 0, b_in, 0, H, 0, 128, H16, 0, NN, 1);

        for (int layer = 0; layer < 2; ++layer) {
            const unsigned short* Wls = layer ? W2s : W1s;
            const float* bl = layer ? b2 : b1;
            const float* ql = layer ? q2 : q1;
            const float* lg = layer ? ln2g : ln1g;
            const float* lb = layer ? ln2b : ln1b;
            float* hout = layer ? (HS + (size_t)t * NN * 128) : H;
            unsigned short* hout16 = layer ? (unsigned short*)0 : H16;

            agg16_kernel<<<dim3((RR * NN) / 4), blk, 0, stream>>>(H16, SRCW, ROWS, AGG16);
            // conv projection, bf16 in-place: AGG16 <- AGG16 @ W + b
            mmb<<<dim3(G64, 1, RR), blk, 0, stream>>>(
                (const void*)AGG16, 1, (long)NN * 128, 128,
                Wls, 16384, bl, 128, (float*)0, 0, 0, AGG16, (long)NN * 128, NN, 0);
            attnln_kernel<<<dim3(NN / 4), blk, 0, stream>>>(AGG16, H, ql, lg, lb, hout, hout16);
        }
    }

    // ---------- phase B: GRU over T (outs alias HS[t]) ----------
    hipMemsetAsync(HST, 0, (size_t)NN * 128 * 4, stream);
    for (int t = 0; t < TT; ++t) {
        float* xt = HS + (size_t)t * NN * 128;
        for (int mode = 0; mode < 3; ++mode)
            grub<<<dim3(G64), blk, 0, stream>>>(
                xt, HST, gWihs, gbih, gWhhs, gbhh, S1, S2, xt, mode);
    }

    // ---------- phase C: temporal attn + tab + classifier ----------
    temporal_kernel<<<dim3(NN / 4), blk, 0, stream>>>(HS, tq, ZB);

    mmb<<<dim3(G64, 1, 1), blk, 0, stream>>>(
        (const void*)(feat + (size_t)3 * NN * 128), 0, 0, 128,
        tW1s, 0, tb1, 0, TABH, 0, 128, (unsigned short*)0, 0, NN, 1);
    mmb<<<dim3(G64, 1, 1), blk, 0, stream>>>(
        (const void*)TABH, 0, 0, 128,
        tW2s, 0, tb2, 0, ZB + 256, 0, 384, (unsigned short*)0, 0, NN, 1);

    mm128<<<dim3(G64, 1, 1), blk, 0, stream>>>(
        ZB, 0, 384, cW1, 0, 128, cb1, 0, TABH, 0, 128, NN, 3, 1);

    dot_kernel<<<dim3(NN / 4), blk, 0, stream>>>(TABH, cW2, cb2, outv);
}

// Round 6
// 2722.545 us; speedup vs baseline: 1.7073x; 1.2094x over previous
//
#include <hip/hip_runtime.h>
#include <hip/hip_bf16.h>
#include <math.h>

#define NN 50000
#define TT 4
#define RR 3
#define EE 500000

typedef __attribute__((ext_vector_type(8))) short bf16x8;
typedef __attribute__((ext_vector_type(4))) float f32x4;

__device__ inline unsigned short f2b(float f)
{
    union { __hip_bfloat16 h; unsigned short u; } cv;
    cv.h = __float2bfloat16(f);
    return cv.u;
}
__device__ inline float b2f(unsigned short u)
{
    union { unsigned int u; float f; } cv;
    cv.u = ((unsigned int)u) << 16;
    return cv.f;
}
__device__ inline bf16x8 pack8(float4 a, float4 b)
{
    bf16x8 r;
    r[0] = (short)f2b(a.x); r[1] = (short)f2b(a.y); r[2] = (short)f2b(a.z); r[3] = (short)f2b(a.w);
    r[4] = (short)f2b(b.x); r[5] = (short)f2b(b.y); r[6] = (short)f2b(b.z); r[7] = (short)f2b(b.w);
    return r;
}

// ---------------- diagnostic fill ----------------

__global__ __launch_bounds__(256)
void diag_kernel(float* __restrict__ out, float v)
{
    int i = blockIdx.x * 256 + threadIdx.x;
    if (i < NN) out[i] = v;
}

// ---------------- weight swizzle: (S,128,C) fp32 -> MFMA B-frag bf16 ----------

__global__ __launch_bounds__(256)
void wswz_kernel(const float* __restrict__ W, unsigned short* __restrict__ dst, int C, int S)
{
    int idx = blockIdx.x * 256 + threadIdx.x;
    int per = 128 * C;
    if (idx >= S * per) return;
    int s = idx / per, rem = idx - s * per;
    int j = rem & 7;
    int lane = (rem >> 3) & 63;
    int blk = rem >> 9;
    int ncg = C >> 4;
    int kc = blk / ncg, cg = blk - kc * ncg;
    int k = kc * 32 + (lane >> 4) * 8 + j;
    int c = cg * 16 + (lane & 15);
    dst[idx] = f2b(W[(size_t)s * 128 * C + (size_t)k * C + c]);
}

// ---------------- CSR build (per t: R graphs) ----------------

__global__ __launch_bounds__(256)
void count_kernel(const int* __restrict__ dst, int* __restrict__ cnt)
{
    int g = blockIdx.y;
    int e = blockIdx.x * 256 + threadIdx.x;
    if (e >= EE) return;
    int d = dst[(size_t)g * EE + e];
    atomicAdd(&cnt[(size_t)g * NN + d], 1);
}

__global__ __launch_bounds__(1024)
void scan_kernel(int* __restrict__ cnt, int* __restrict__ rows)
{
    int g = blockIdx.x;
    int tid = threadIdx.x;
    const int CH = (NN + 1023) / 1024;
    int s0 = tid * CH;
    int s1 = s0 + CH; if (s1 > NN) s1 = NN;
    int* c = cnt + (size_t)g * NN;
    int* ro = rows + (size_t)g * (NN + 1);
    int sum = 0;
    for (int i = s0; i < s1; ++i) sum += c[i];
    __shared__ int sd[1024];
    sd[tid] = sum;
    __syncthreads();
    for (int off = 1; off < 1024; off <<= 1) {
        int v = 0;
        if (tid >= off) v = sd[tid - off];
        __syncthreads();
        sd[tid] += v;
        __syncthreads();
    }
    int total = sd[1023];
    int prefix = (tid == 0) ? 0 : sd[tid - 1];
    for (int i = s0; i < s1; ++i) {
        int cv = c[i];
        ro[i] = prefix;
        c[i] = prefix;
        prefix += cv;
    }
    if (tid == 0) ro[NN] = total;
}

__global__ __launch_bounds__(256)
void fill_kernel(const int* __restrict__ src, const int* __restrict__ dst,
                 const float* __restrict__ ew, int* __restrict__ cur,
                 int2* __restrict__ srcw)
{
    int g = blockIdx.y;
    int e = blockIdx.x * 256 + threadIdx.x;
    if (e >= EE) return;
    size_t idx = (size_t)g * EE + e;
    int d = dst[idx];
    int pos = atomicAdd(&cur[(size_t)g * NN + d], 1);
    int2 p;
    p.x = src[idx];
    p.y = __float_as_int(ew[idx]);
    srcw[(size_t)g * EE + pos] = p;
}

// ---------------- conv gather-aggregate, 8-deep pipelined edge loop ----------

__global__ __launch_bounds__(256)
void agg16_kernel(const unsigned short* __restrict__ x16,  // (N,128) bf16
                  const int2* __restrict__ srcw,           // (R,E)
                  const int* __restrict__ rows,            // (R,N+1)
                  unsigned short* __restrict__ agg16)      // (R,N,128) bf16
{
    int wid = (blockIdx.x * 256 + threadIdx.x) >> 6;
    int lane = threadIdx.x & 63;
    if (wid >= RR * NN) return;
    int r = wid / NN;
    int n = wid - r * NN;
    const int* rs = rows + (size_t)r * (NN + 1);
    int e0 = rs[n], e1 = rs[n + 1];
    const int2* sw = srcw + (size_t)r * EE;
    const int co = lane * 2;
    float ax = 0.f, ay = 0.f;
    int e = e0;
    // batch of 8: load all edge records, then issue 8 independent row gathers
    for (; e + 8 <= e1; e += 8) {
        int2 p0 = sw[e + 0], p1 = sw[e + 1], p2 = sw[e + 2], p3 = sw[e + 3];
        int2 p4 = sw[e + 4], p5 = sw[e + 5], p6 = sw[e + 6], p7 = sw[e + 7];
        unsigned int v0 = *(const unsigned int*)(x16 + (size_t)p0.x * 128 + co);
        unsigned int v1 = *(const unsigned int*)(x16 + (size_t)p1.x * 128 + co);
        unsigned int v2 = *(const unsigned int*)(x16 + (size_t)p2.x * 128 + co);
        unsigned int v3 = *(const unsigned int*)(x16 + (size_t)p3.x * 128 + co);
        unsigned int v4 = *(const unsigned int*)(x16 + (size_t)p4.x * 128 + co);
        unsigned int v5 = *(const unsigned int*)(x16 + (size_t)p5.x * 128 + co);
        unsigned int v6 = *(const unsigned int*)(x16 + (size_t)p6.x * 128 + co);
        unsigned int v7 = *(const unsigned int*)(x16 + (size_t)p7.x * 128 + co);
        float w0 = __int_as_float(p0.y), w1 = __int_as_float(p1.y);
        float w2 = __int_as_float(p2.y), w3 = __int_as_float(p3.y);
        float w4 = __int_as_float(p4.y), w5 = __int_as_float(p5.y);
        float w6 = __int_as_float(p6.y), w7 = __int_as_float(p7.y);
        ax += w0 * b2f((unsigned short)(v0 & 0xffffu)) + w1 * b2f((unsigned short)(v1 & 0xffffu))
            + w2 * b2f((unsigned short)(v2 & 0xffffu)) + w3 * b2f((unsigned short)(v3 & 0xffffu))
            + w4 * b2f((unsigned short)(v4 & 0xffffu)) + w5 * b2f((unsigned short)(v5 & 0xffffu))
            + w6 * b2f((unsigned short)(v6 & 0xffffu)) + w7 * b2f((unsigned short)(v7 & 0xffffu));
        ay += w0 * b2f((unsigned short)(v0 >> 16)) + w1 * b2f((unsigned short)(v1 >> 16))
            + w2 * b2f((unsigned short)(v2 >> 16)) + w3 * b2f((unsigned short)(v3 >> 16))
            + w4 * b2f((unsigned short)(v4 >> 16)) + w5 * b2f((unsigned short)(v5 >> 16))
            + w6 * b2f((unsigned short)(v6 >> 16)) + w7 * b2f((unsigned short)(v7 >> 16));
    }
    for (; e < e1; ++e) {
        int2 p = sw[e];
        float w = __int_as_float(p.y);
        unsigned int v = *(const unsigned int*)(x16 + (size_t)p.x * 128 + co);
        ax += w * b2f((unsigned short)(v & 0xffffu));
        ay += w * b2f((unsigned short)(v >> 16));
    }
    float inv = 1.0f / fmaxf((float)(e1 - e0), 1.0f);
    unsigned int o = (unsigned int)f2b(ax * inv) | ((unsigned int)f2b(ay * inv) << 16);
    *(unsigned int*)(agg16 + ((size_t)r * NN + n) * 128 + co) = o;
}

// ---------------- MFMA matmul: out = act(in @ W + b), K=128, 128 cols --------

__global__ __launch_bounds__(256)
void mmb(const void* in, int in_bf16, long in_zs, int ldin,
         const unsigned short* __restrict__ Ws, long w_zs,
         const float* __restrict__ bias, long b_zs,
         float* out, long out_zs, int ldout,
         unsigned short* out16, long out16_zs,
         int rows, int act)
{
    const int tid = threadIdx.x;
    const int wv = tid >> 6, l = tid & 63;
    const int z = blockIdx.z;
    const int r0 = blockIdx.x * 64 + wv * 16;
    const int lk = (l >> 4) * 8;
    int rowA = r0 + (l & 15);
    int rowc = rowA < rows ? rowA : rows - 1;

    bf16x8 a[4];
    if (in_bf16) {
        const unsigned short* inb = (const unsigned short*)in + (size_t)z * in_zs
                                    + (size_t)rowc * ldin + lk;
#pragma unroll
        for (int kc = 0; kc < 4; ++kc) {
            uint4 u = *(const uint4*)(inb + kc * 32);
            a[kc] = *(bf16x8*)&u;
        }
    } else {
        const float* inf = (const float*)in + (size_t)z * in_zs
                           + (size_t)rowc * ldin + lk;
#pragma unroll
        for (int kc = 0; kc < 4; ++kc) {
            float4 u0 = *(const float4*)(inf + kc * 32);
            float4 u1 = *(const float4*)(inf + kc * 32 + 4);
            a[kc] = pack8(u0, u1);
        }
    }

    const unsigned short* Wz = Ws + (size_t)z * w_zs;
    const float* bz = bias + (size_t)z * b_zs;
    float* oz = out ? out + (size_t)z * out_zs : (float*)0;
    unsigned short* o16z = out16 ? out16 + (size_t)z * out16_zs : (unsigned short*)0;
    const int colbase = l & 15;
    const int rbase = r0 + (l >> 4) * 4;

#pragma unroll
    for (int cg = 0; cg < 8; ++cg) {
        f32x4 acc = {0.f, 0.f, 0.f, 0.f};
#pragma unroll
        for (int kc = 0; kc < 4; ++kc) {
            uint4 bu = *(const uint4*)(Wz + ((size_t)(kc * 8 + cg) * 64 + l) * 8);
            acc = __builtin_amdgcn_mfma_f32_16x16x32_bf16(a[kc], *(bf16x8*)&bu, acc, 0, 0, 0);
        }
        int col = cg * 16 + colbase;
        float bvv = bz[col];
#pragma unroll
        for (int j = 0; j < 4; ++j) {
            int gr = rbase + j;
            if (gr >= rows) continue;
            float v = acc[j] + bvv;
            if (act) v = fmaxf(v, 0.f);
            if (oz) oz[(size_t)gr * ldout + col] = v;
            if (o16z) o16z[(size_t)gr * 128 + col] = f2b(v);
        }
    }
}

// ---------------- fully-fused MFMA GRU step: h,outs <- GRU(x, h) -------------
// Computes all three gate groups (r,z,n) of gi AND gh per column-group and
// applies the epilogue in-register. outs may alias x (wave reads its 16x128
// block before any write; per-cg h reads/writes touch disjoint columns).

__global__ __launch_bounds__(256)
void grub_all(const float* x, float* h,
              const unsigned short* __restrict__ Wis, const float* __restrict__ bi,
              const unsigned short* __restrict__ Whs, const float* __restrict__ bh,
              float* outs)
{
    const int tid = threadIdx.x;
    const int wv = tid >> 6, l = tid & 63;
    const int r0 = blockIdx.x * 64 + wv * 16;
    const int lk = (l >> 4) * 8;
    int rowA = r0 + (l & 15);
    int rowc = rowA < NN ? rowA : NN - 1;

    bf16x8 ax[4], hx[4];
    {
        const float* bx = x + (size_t)rowc * 128 + lk;
        const float* bhp = h + (size_t)rowc * 128 + lk;
#pragma unroll
        for (int kc = 0; kc < 4; ++kc) {
            ax[kc] = pack8(*(const float4*)(bx + kc * 32), *(const float4*)(bx + kc * 32 + 4));
            hx[kc] = pack8(*(const float4*)(bhp + kc * 32), *(const float4*)(bhp + kc * 32 + 4));
        }
    }
    const int colbase = l & 15;
    const int rbase = r0 + (l >> 4) * 4;

#pragma unroll
    for (int cg = 0; cg < 8; ++cg) {
        f32x4 air = {0.f,0.f,0.f,0.f}, ahr = {0.f,0.f,0.f,0.f};
        f32x4 aiz = {0.f,0.f,0.f,0.f}, ahz = {0.f,0.f,0.f,0.f};
        f32x4 ain = {0.f,0.f,0.f,0.f}, ahn = {0.f,0.f,0.f,0.f};
#pragma unroll
        for (int kc = 0; kc < 4; ++kc) {
            uint4 br = *(const uint4*)(Wis + ((size_t)(kc * 24 + 0 + cg) * 64 + l) * 8);
            uint4 hr = *(const uint4*)(Whs + ((size_t)(kc * 24 + 0 + cg) * 64 + l) * 8);
            uint4 bz = *(const uint4*)(Wis + ((size_t)(kc * 24 + 8 + cg) * 64 + l) * 8);
            uint4 hz = *(const uint4*)(Whs + ((size_t)(kc * 24 + 8 + cg) * 64 + l) * 8);
            uint4 bn = *(const uint4*)(Wis + ((size_t)(kc * 24 + 16 + cg) * 64 + l) * 8);
            uint4 hn = *(const uint4*)(Whs + ((size_t)(kc * 24 + 16 + cg) * 64 + l) * 8);
            air = __builtin_amdgcn_mfma_f32_16x16x32_bf16(ax[kc], *(bf16x8*)&br, air, 0, 0, 0);
            ahr = __builtin_amdgcn_mfma_f32_16x16x32_bf16(hx[kc], *(bf16x8*)&hr, ahr, 0, 0, 0);
            aiz = __builtin_amdgcn_mfma_f32_16x16x32_bf16(ax[kc], *(bf16x8*)&bz, aiz, 0, 0, 0);
            ahz = __builtin_amdgcn_mfma_f32_16x16x32_bf16(hx[kc], *(bf16x8*)&hz, ahz, 0, 0, 0);
            ain = __builtin_amdgcn_mfma_f32_16x16x32_bf16(ax[kc], *(bf16x8*)&bn, ain, 0, 0, 0);
            ahn = __builtin_amdgcn_mfma_f32_16x16x32_bf16(hx[kc], *(bf16x8*)&hn, ahn, 0, 0, 0);
        }
        int col = cg * 16 + colbase;
        float bir = bi[col],       bhr = bh[col];
        float biz = bi[128 + col], bhz = bh[128 + col];
        float bin = bi[256 + col], bhn = bh[256 + col];
#pragma unroll
        for (int j = 0; j < 4; ++j) {
            int gr = rbase + j;
            if (gr >= NN) continue;
            float r_ = 1.f / (1.f + __expf(-(air[j] + bir + ahr[j] + bhr)));
            float z_ = 1.f / (1.f + __expf(-(aiz[j] + biz + ahz[j] + bhz)));
            float n_ = tanhf(ain[j] + bin + r_ * (ahn[j] + bhn));
            float hv = h[(size_t)gr * 128 + col];
            float o = (1.f - z_) * n_ + z_ * hv;
            h[(size_t)gr * 128 + col] = o;
            outs[(size_t)gr * 128 + col] = o;
        }
    }
}

// ---------------- classifier: out = relu(Z @ cW1 + cb1) . cW2 + cb2 ----------
// K = 384, 128 hidden cols; dot fused into the epilogue.

__global__ __launch_bounds__(256)
void mm_cls(const float* __restrict__ in,   // (N,384)
            const float* __restrict__ W,    // (384,128)
            const float* __restrict__ b1_,  // (128)
            const float* __restrict__ w2,   // (128)
            const float* __restrict__ b2_,  // (1)
            float* __restrict__ outv, int rows)
{
    __shared__ float lds[64 * 128];
    const int row0 = blockIdx.x * 64;
    const int tid = threadIdx.x;
    const int tx = tid & 31;
    const int ty = tid >> 5;
    float acc[8][4];
#pragma unroll
    for (int i = 0; i < 8; ++i) { acc[i][0] = 0.f; acc[i][1] = 0.f; acc[i][2] = 0.f; acc[i][3] = 0.f; }
    for (int kc = 0; kc < 3; ++kc) {
        __syncthreads();
        {
            const int col4 = tx * 4;
#pragma unroll
            for (int p = 0; p < 8; ++p) {
                const int rloc = p * 8 + ty;
                const int grow = row0 + rloc;
                float4 v = make_float4(0.f, 0.f, 0.f, 0.f);
                if (grow < rows) v = *(const float4*)(in + (long)grow * 384 + kc * 128 + col4);
                *(float4*)(&lds[rloc * 128 + col4]) = v;
            }
        }
        __syncthreads();
        const float* Wk = W + (long)kc * 128 * 128;
        for (int k4 = 0; k4 < 128; k4 += 4) {
            const float4 w0 = *(const float4*)(Wk + (long)(k4 + 0) * 128 + tx * 4);
            const float4 w1 = *(const float4*)(Wk + (long)(k4 + 1) * 128 + tx * 4);
            const float4 w2v = *(const float4*)(Wk + (long)(k4 + 2) * 128 + tx * 4);
            const float4 w3 = *(const float4*)(Wk + (long)(k4 + 3) * 128 + tx * 4);
#pragma unroll
            for (int i = 0; i < 8; ++i) {
                const float4 xv = *(const float4*)(&lds[(ty * 8 + i) * 128 + k4]);
                acc[i][0] += xv.x * w0.x + xv.y * w1.x + xv.z * w2v.x + xv.w * w3.x;
                acc[i][1] += xv.x * w0.y + xv.y * w1.y + xv.z * w2v.y + xv.w * w3.y;
                acc[i][2] += xv.x * w0.z + xv.y * w1.z + xv.z * w2v.z + xv.w * w3.z;
                acc[i][3] += xv.x * w0.w + xv.y * w1.w + xv.z * w2v.w + xv.w * w3.w;
            }
        }
    }
    const float4 bv = *(const float4*)(b1_ + tx * 4);
    const float4 wsel = *(const float4*)(w2 + tx * 4);
    const float cb2v = b2_[0];
#pragma unroll
    for (int i = 0; i < 8; ++i) {
        const int grow = row0 + ty * 8 + i;
        float h0 = fmaxf(acc[i][0] + bv.x, 0.f);
        float h1 = fmaxf(acc[i][1] + bv.y, 0.f);
        float h2 = fmaxf(acc[i][2] + bv.z, 0.f);
        float h3 = fmaxf(acc[i][3] + bv.w, 0.f);
        float partial = h0 * wsel.x + h1 * wsel.y + h2 * wsel.z + h3 * wsel.w;
#pragma unroll
        for (int m = 16; m; m >>= 1) partial += __shfl_xor(partial, m);
        if (tx == 0 && grow < rows) outv[grow] = partial + cb2v;
    }
}

// ---------------- fused rel-attn + relu + residual + LayerNorm ----------------

__device__ inline float wred(float v)
{
#pragma unroll
    for (int m = 32; m; m >>= 1) v += __shfl_xor(v, m);
    return v;
}

__global__ __launch_bounds__(256)
void attnln_kernel(const unsigned short* __restrict__ agg16, // (R,N,128) bf16
                   const float* hin,                          // (N,128), may alias hout
                   const float* __restrict__ q,
                   const float* __restrict__ g,
                   const float* __restrict__ b,
                   float* hout,
                   unsigned short* hout16)                    // optional bf16 mirror
{
    int wid = (blockIdx.x * 256 + threadIdx.x) >> 6;
    int lane = threadIdx.x & 63;
    if (wid >= NN) return;
    int n = wid;
    float2 qv = *(const float2*)(q + lane * 2);
    float sx[3], sy[3], sc[3];
#pragma unroll
    for (int r = 0; r < 3; ++r) {
        unsigned int v = *(const unsigned int*)(agg16 + ((size_t)r * NN + n) * 128 + lane * 2);
        sx[r] = b2f((unsigned short)(v & 0xffffu));
        sy[r] = b2f((unsigned short)(v >> 16));
        sc[r] = wred(tanhf(sx[r]) * qv.x + tanhf(sy[r]) * qv.y);
    }
    float mx = fmaxf(sc[0], fmaxf(sc[1], sc[2]));
    float e0 = __expf(sc[0] - mx), e1 = __expf(sc[1] - mx), e2 = __expf(sc[2] - mx);
    float isum = 1.f / (e0 + e1 + e2);
    float axv = (e0 * sx[0] + e1 * sx[1] + e2 * sx[2]) * isum;
    float ayv = (e0 * sy[0] + e1 * sy[1] + e2 * sy[2]) * isum;
    float2 hv = *(const float2*)(hin + (size_t)n * 128 + lane * 2);
    float ux = hv.x + fmaxf(axv, 0.f);
    float uy = hv.y + fmaxf(ayv, 0.f);
    float mean = wred(ux + uy) * (1.f / 128.f);
    float dx = ux - mean, dy = uy - mean;
    float var = wred(dx * dx + dy * dy) * (1.f / 128.f);
    float rstd = rsqrtf(var + 1e-5f);
    float2 gv = *(const float2*)(g + lane * 2);
    float2 bv = *(const float2*)(b + lane * 2);
    float2 o;
    o.x = dx * rstd * gv.x + bv.x;
    o.y = dy * rstd * gv.y + bv.y;
    *(float2*)(hout + (size_t)n * 128 + lane * 2) = o;
    if (hout16) {
        unsigned int p = (unsigned int)f2b(o.x) | ((unsigned int)f2b(o.y) << 16);
        *(unsigned int*)(hout16 + (size_t)n * 128 + lane * 2) = p;
    }
}

// ---------------- temporal attention (also emits `last`) ----------------

__global__ __launch_bounds__(256)
void temporal_kernel(const float* __restrict__ outs, // (T,N,128)
                     const float* __restrict__ tq,
                     float* __restrict__ zbuf)       // (N,384)
{
    int wid = (blockIdx.x * 256 + threadIdx.x) >> 6;
    int lane = threadIdx.x & 63;
    if (wid >= NN) return;
    int n = wid;
    float2 qv = *(const float2*)(tq + lane * 2);
    float2 o[4];
    float sc[4];
#pragma unroll
    for (int t = 0; t < 4; ++t) {
        o[t] = *(const float2*)(outs + ((size_t)t * NN + n) * 128 + lane * 2);
        sc[t] = wred(tanhf(o[t].x) * qv.x + tanhf(o[t].y) * qv.y);
    }
    float mx = fmaxf(fmaxf(sc[0], sc[1]), fmaxf(sc[2], sc[3]));
    float e[4];
    float sum = 0.f;
#pragma unroll
    for (int t = 0; t < 4; ++t) { e[t] = __expf(sc[t] - mx); sum += e[t]; }
    float isum = 1.f / sum;
    float axv = 0.f, ayv = 0.f;
#pragma unroll
    for (int t = 0; t < 4; ++t) { axv += e[t] * o[t].x; ayv += e[t] * o[t].y; }
    axv *= isum; ayv *= isum;
    float* zr = zbuf + (size_t)n * 384;
    *(float2*)(zr + lane * 2) = o[3];
    float2 at; at.x = axv; at.y = ayv;
    *(float2*)(zr + 128 + lane * 2) = at;
}

// ---------------- launch ----------------

extern "C" void kernel_launch(void* const* d_in, const int* in_sizes, int n_in,
                              void* d_out, int out_size, void* d_ws, size_t ws_size,
                              hipStream_t stream)
{
    const float* feat = (const float*)d_in[0];
    const int* srcp   = (const int*)d_in[1];
    const int* dstp   = (const int*)d_in[2];
    const float* ewp  = (const float*)d_in[3];
    const float* W_in = (const float*)d_in[4];
    const float* b_in = (const float*)d_in[5];
    const float* W1   = (const float*)d_in[6];
    const float* b1   = (const float*)d_in[7];
    const float* W2   = (const float*)d_in[8];
    const float* b2   = (const float*)d_in[9];
    const float* q1   = (const float*)d_in[10];
    const float* q2   = (const float*)d_in[11];
    const float* ln1g = (const float*)d_in[12];
    const float* ln1b = (const float*)d_in[13];
    const float* ln2g = (const float*)d_in[14];
    const float* ln2b = (const float*)d_in[15];
    const float* gWih = (const float*)d_in[16];
    const float* gbih = (const float*)d_in[17];
    const float* gWhh = (const float*)d_in[18];
    const float* gbhh = (const float*)d_in[19];
    const float* tq   = (const float*)d_in[20];
    const float* tW1  = (const float*)d_in[21];
    const float* tb1  = (const float*)d_in[22];
    const float* tW2  = (const float*)d_in[23];
    const float* tb2  = (const float*)d_in[24];
    const float* cW1  = (const float*)d_in[25];
    const float* cb1  = (const float*)d_in[26];
    const float* cW2  = (const float*)d_in[27];
    const float* cb2  = (const float*)d_in[28];
    float* outv = (float*)d_out;
    (void)in_sizes; (void)n_in; (void)out_size;

    // ---- ws layout (bytes), peak ~205.3 MB ----
    const size_t o_HS    = 0;                      // (T,N,128) fp32 = 102,400,000
    const size_t o_POOL  = 102400000;
    const size_t o_AGG16 = o_POOL;                 // phase A: (R,N,128) bf16
    const size_t o_H16   = o_POOL + 38400000;      // phase A: (N,128) bf16
    const size_t o_SRCW  = o_POOL + 51200000;      // phase A: (R,E) int2
    const size_t o_ROWS  = o_POOL + 63200000;
    const size_t o_CURS  = o_POOL + 63800064;
    const size_t o_ZB    = o_POOL;                 // phase C: (N,384) fp32
    const size_t o_H     = o_POOL + 76800000;      // (N,128) fp32 (H/HST/TABH)
    const size_t o_WSZ   = o_H + 25600000;
    const size_t NEED    = o_WSZ + 491520;

    if (ws_size < NEED) {
        diag_kernel<<<dim3((NN + 255) / 256), dim3(256), 0, stream>>>(outv, (float)(ws_size >> 20));
        return;
    }

    char* wsb = (char*)d_ws;
    float* HS             = (float*)(wsb + o_HS);
    unsigned short* AGG16 = (unsigned short*)(wsb + o_AGG16);
    unsigned short* H16   = (unsigned short*)(wsb + o_H16);
    int2*  SRCW           = (int2*)(wsb + o_SRCW);
    int*   ROWS           = (int*)(wsb + o_ROWS);
    int*   CURS           = (int*)(wsb + o_CURS);
    float* ZB             = (float*)(wsb + o_ZB);
    float* H              = (float*)(wsb + o_H);
    float* HST            = (float*)(wsb + o_H);
    float* TABH           = (float*)(wsb + o_H);
    unsigned short* WSZ   = (unsigned short*)(wsb + o_WSZ);

    unsigned short* Wins  = WSZ;
    unsigned short* W1s   = WSZ + 16384;
    unsigned short* W2s   = WSZ + 65536;
    unsigned short* gWihs = WSZ + 114688;
    unsigned short* gWhhs = WSZ + 163840;
    unsigned short* tW1s  = WSZ + 212992;
    unsigned short* tW2s  = WSZ + 229376;

    const dim3 blk(256);
    const int G64 = (NN + 63) / 64;
    const dim3 gE((EE + 255) / 256, RR);

    // ---------- weight swizzle ----------
    wswz_kernel<<<dim3((1 * 16384 + 255) / 256), blk, 0, stream>>>(W_in, Wins, 128, 1);
    wswz_kernel<<<dim3((3 * 16384 + 255) / 256), blk, 0, stream>>>(W1,   W1s,  128, 3);
    wswz_kernel<<<dim3((3 * 16384 + 255) / 256), blk, 0, stream>>>(W2,   W2s,  128, 3);
    wswz_kernel<<<dim3((1 * 49152 + 255) / 256), blk, 0, stream>>>(gWih, gWihs, 384, 1);
    wswz_kernel<<<dim3((1 * 49152 + 255) / 256), blk, 0, stream>>>(gWhh, gWhhs, 384, 1);
    wswz_kernel<<<dim3((1 * 16384 + 255) / 256), blk, 0, stream>>>(tW1,  tW1s, 128, 1);
    wswz_kernel<<<dim3((1 * 16384 + 255) / 256), blk, 0, stream>>>(tW2,  tW2s, 128, 1);

    // ---------- phase A: spatial layers, t-outer ----------
    for (int t = 0; t < TT; ++t) {
        const size_t eoff = (size_t)t * RR * EE;
        hipMemsetAsync(CURS, 0, (size_t)RR * NN * 4, stream);
        count_kernel<<<gE, blk, 0, stream>>>(dstp + eoff, CURS);
        scan_kernel<<<dim3(RR), dim3(1024), 0, stream>>>(CURS, ROWS);
        fill_kernel<<<gE, blk, 0, stream>>>(srcp + eoff, dstp + eoff, ewp + eoff, CURS, SRCW);

        mmb<<<dim3(G64, 1, 1), blk, 0, stream>>>(
            (const void*)(feat + (size_t)t * NN * 128), 0, 0, 128,
            Wins, 0, b_in, 0, H, 0, 128, H16, 0, NN, 1);

        for (int layer = 0; layer < 2; ++layer) {
            const unsigned short* Wls = layer ? W2s : W1s;
            const float* bl = layer ? b2 : b1;
            const float* ql = layer ? q2 : q1;
            const float* lg = layer ? ln2g : ln1g;
            const float* lb = layer ? ln2b : ln1b;
            float* hout = layer ? (HS + (size_t)t * NN * 128) : H;
            unsigned short* hout16 = layer ? (unsigned short*)0 : H16;

            agg16_kernel<<<dim3((RR * NN) / 4), blk, 0, stream>>>(H16, SRCW, ROWS, AGG16);
            mmb<<<dim3(G64, 1, RR), blk, 0, stream>>>(
                (const void*)AGG16, 1, (long)NN * 128, 128,
                Wls, 16384, bl, 128, (float*)0, 0, 0, AGG16, (long)NN * 128, NN, 0);
            attnln_kernel<<<dim3(NN / 4), blk, 0, stream>>>(AGG16, H, ql, lg, lb, hout, hout16);
        }
    }

    // ---------- phase B: fused GRU over T (outs alias HS[t]) ----------
    hipMemsetAsync(HST, 0, (size_t)NN * 128 * 4, stream);
    for (int t = 0; t < TT; ++t) {
        float* xt = HS + (size_t)t * NN * 128;
        grub_all<<<dim3(G64), blk, 0, stream>>>(xt, HST, gWihs, gbih, gWhhs, gbhh, xt);
    }

    // ---------- phase C: temporal attn + tab + classifier ----------
    temporal_kernel<<<dim3(NN / 4), blk, 0, stream>>>(HS, tq, ZB);

    mmb<<<dim3(G64, 1, 1), blk, 0, stream>>>(
        (const void*)(feat + (size_t)3 * NN * 128), 0, 0, 128,
        tW1s, 0, tb1, 0, TABH, 0, 128, (unsigned short*)0, 0, NN, 1);
    mmb<<<dim3(G64, 1, 1), blk, 0, stream>>>(
        (const void*)TABH, 0, 0, 128,
        tW2s, 0, tb2, 0, ZB + 256, 0, 384, (unsigned short*)0, 0, NN, 1);

    mm_cls<<<dim3(G64), blk, 0, stream>>>(ZB, cW1, cb1, cW2, cb2, outv, NN);
}

// Round 8
// 2343.991 us; speedup vs baseline: 1.9830x; 1.1615x over previous
//
#include <hip/hip_runtime.h>
#include <hip/hip_bf16.h>
#include <math.h>

#define NN 50000
#define TT 4
#define RR 3
#define EE 500000

typedef __attribute__((ext_vector_type(8))) short bf16x8;
typedef __attribute__((ext_vector_type(4))) float f32x4;

__device__ inline unsigned short f2b(float f)
{
    union { __hip_bfloat16 h; unsigned short u; } cv;
    cv.h = __float2bfloat16(f);
    return cv.u;
}
__device__ inline float b2f(unsigned short u)
{
    union { unsigned int u; float f; } cv;
    cv.u = ((unsigned int)u) << 16;
    return cv.f;
}
__device__ inline bf16x8 pack8(float4 a, float4 b)
{
    bf16x8 r;
    r[0] = (short)f2b(a.x); r[1] = (short)f2b(a.y); r[2] = (short)f2b(a.z); r[3] = (short)f2b(a.w);
    r[4] = (short)f2b(b.x); r[5] = (short)f2b(b.y); r[6] = (short)f2b(b.z); r[7] = (short)f2b(b.w);
    return r;
}

// ---------------- diagnostic fill ----------------

__global__ __launch_bounds__(256)
void diag_kernel(float* __restrict__ out, float v)
{
    int i = blockIdx.x * 256 + threadIdx.x;
    if (i < NN) out[i] = v;
}

// ---------------- weight swizzle: (S,128,C) fp32 -> MFMA B-frag bf16 ----------

__global__ __launch_bounds__(256)
void wswz_kernel(const float* __restrict__ W, unsigned short* __restrict__ dst, int C, int S)
{
    int idx = blockIdx.x * 256 + threadIdx.x;
    int per = 128 * C;
    if (idx >= S * per) return;
    int s = idx / per, rem = idx - s * per;
    int j = rem & 7;
    int lane = (rem >> 3) & 63;
    int blk = rem >> 9;
    int ncg = C >> 4;
    int kc = blk / ncg, cg = blk - kc * ncg;
    int k = kc * 32 + (lane >> 4) * 8 + j;
    int c = cg * 16 + (lane & 15);
    dst[idx] = f2b(W[(size_t)s * 128 * C + (size_t)k * C + c]);
}

// ---------------- CSR build (all 12 graphs at once for count/scan) -----------

__global__ __launch_bounds__(256)
void count_kernel(const int* __restrict__ dst, int* __restrict__ cnt)
{
    int g = blockIdx.y;
    int e = blockIdx.x * 256 + threadIdx.x;
    if (e >= EE) return;
    int d = dst[(size_t)g * EE + e];
    atomicAdd(&cnt[(size_t)g * NN + d], 1);
}

__global__ __launch_bounds__(1024)
void scan_kernel(int* __restrict__ cnt, int* __restrict__ rows)
{
    int g = blockIdx.x;
    int tid = threadIdx.x;
    const int CH = (NN + 1023) / 1024;
    int s0 = tid * CH;
    int s1 = s0 + CH; if (s1 > NN) s1 = NN;
    int* c = cnt + (size_t)g * NN;
    int* ro = rows + (size_t)g * (NN + 1);
    int sum = 0;
    for (int i = s0; i < s1; ++i) sum += c[i];
    __shared__ int sd[1024];
    sd[tid] = sum;
    __syncthreads();
    for (int off = 1; off < 1024; off <<= 1) {
        int v = 0;
        if (tid >= off) v = sd[tid - off];
        __syncthreads();
        sd[tid] += v;
        __syncthreads();
    }
    int total = sd[1023];
    int prefix = (tid == 0) ? 0 : sd[tid - 1];
    for (int i = s0; i < s1; ++i) {
        int cv = c[i];
        ro[i] = prefix;
        c[i] = prefix;
        prefix += cv;
    }
    if (tid == 0) ro[NN] = total;
}

__global__ __launch_bounds__(256)
void fill_kernel(const int* __restrict__ src, const int* __restrict__ dst,
                 const float* __restrict__ ew, int* __restrict__ cur,
                 int2* __restrict__ srcw)
{
    int g = blockIdx.y;
    int e = blockIdx.x * 256 + threadIdx.x;
    if (e >= EE) return;
    size_t idx = (size_t)g * EE + e;
    int d = dst[idx];
    int pos = atomicAdd(&cur[(size_t)g * NN + d], 1);
    int2 p;
    p.x = src[idx];
    p.y = __float_as_int(ew[idx]);
    srcw[(size_t)g * EE + pos] = p;
}

// ---------------- conv gather-aggregate, predicated 16-batch -----------------

__global__ __launch_bounds__(256)
void agg16_kernel(const unsigned short* __restrict__ x16,  // (N,128) bf16
                  const int2* __restrict__ srcw,           // (R,E)
                  const int* __restrict__ rows,            // (R,N+1)
                  unsigned short* __restrict__ agg16)      // (R,N,128) bf16
{
    int wid = (blockIdx.x * 256 + threadIdx.x) >> 6;
    int lane = threadIdx.x & 63;
    if (wid >= RR * NN) return;
    int r = wid / NN;
    int n = wid - r * NN;
    const int* rs = rows + (size_t)r * (NN + 1);
    int e0 = rs[n], e1 = rs[n + 1];
    const int2* sw = srcw + (size_t)r * EE;
    const int co = lane * 2;
    float ax = 0.f, ay = 0.f;
    // predicated 16-batch: one fully-parallel gather round covers deg<=16 rows
    for (int e = e0; e < e1; e += 16) {
        int2 p[16];
        unsigned int v[16];
#pragma unroll
        for (int i = 0; i < 16; ++i) {
            int idx = (e + i < e1) ? e + i : e1 - 1;
            p[i] = sw[idx];
        }
#pragma unroll
        for (int i = 0; i < 16; ++i)
            v[i] = *(const unsigned int*)(x16 + (size_t)p[i].x * 128 + co);
#pragma unroll
        for (int i = 0; i < 16; ++i) {
            float w = (e + i < e1) ? __int_as_float(p[i].y) : 0.f;
            ax += w * b2f((unsigned short)(v[i] & 0xffffu));
            ay += w * b2f((unsigned short)(v[i] >> 16));
        }
    }
    float inv = 1.0f / fmaxf((float)(e1 - e0), 1.0f);
    unsigned int o = (unsigned int)f2b(ax * inv) | ((unsigned int)f2b(ay * inv) << 16);
    *(unsigned int*)(agg16 + ((size_t)r * NN + n) * 128 + co) = o;
}

// ---------------- MFMA matmul: out = act(in @ W + b), K=128, 128 cols --------

__global__ __launch_bounds__(256)
void mmb(const void* in, int in_bf16, long in_zs, int ldin,
         const unsigned short* __restrict__ Ws, long w_zs,
         const float* __restrict__ bias, long b_zs,
         float* out, long out_zs, int ldout,
         unsigned short* out16, long out16_zs,
         int rows, int act)
{
    const int tid = threadIdx.x;
    const int wv = tid >> 6, l = tid & 63;
    const int z = blockIdx.z;
    const int r0 = blockIdx.x * 64 + wv * 16;
    const int lk = (l >> 4) * 8;
    int rowA = r0 + (l & 15);
    int rowc = rowA < rows ? rowA : rows - 1;

    bf16x8 a[4];
    if (in_bf16) {
        const unsigned short* inb = (const unsigned short*)in + (size_t)z * in_zs
                                    + (size_t)rowc * ldin + lk;
#pragma unroll
        for (int kc = 0; kc < 4; ++kc) {
            uint4 u = *(const uint4*)(inb + kc * 32);
            a[kc] = *(bf16x8*)&u;
        }
    } else {
        const float* inf = (const float*)in + (size_t)z * in_zs
                           + (size_t)rowc * ldin + lk;
#pragma unroll
        for (int kc = 0; kc < 4; ++kc) {
            float4 u0 = *(const float4*)(inf + kc * 32);
            float4 u1 = *(const float4*)(inf + kc * 32 + 4);
            a[kc] = pack8(u0, u1);
        }
    }

    const unsigned short* Wz = Ws + (size_t)z * w_zs;
    const float* bz = bias + (size_t)z * b_zs;
    float* oz = out ? out + (size_t)z * out_zs : (float*)0;
    unsigned short* o16z = out16 ? out16 + (size_t)z * out16_zs : (unsigned short*)0;
    const int colbase = l & 15;
    const int rbase = r0 + (l >> 4) * 4;

#pragma unroll
    for (int cg = 0; cg < 8; ++cg) {
        f32x4 acc = {0.f, 0.f, 0.f, 0.f};
#pragma unroll
        for (int kc = 0; kc < 4; ++kc) {
            uint4 bu = *(const uint4*)(Wz + ((size_t)(kc * 8 + cg) * 64 + l) * 8);
            acc = __builtin_amdgcn_mfma_f32_16x16x32_bf16(a[kc], *(bf16x8*)&bu, acc, 0, 0, 0);
        }
        int col = cg * 16 + colbase;
        float bvv = bz[col];
#pragma unroll
        for (int j = 0; j < 4; ++j) {
            int gr = rbase + j;
            if (gr >= rows) continue;
            float v = acc[j] + bvv;
            if (act) v = fmaxf(v, 0.f);
            if (oz) oz[(size_t)gr * ldout + col] = v;
            if (o16z) o16z[(size_t)gr * 128 + col] = f2b(v);
        }
    }
}

// ---------------- fully-fused MFMA GRU step: h,outs <- GRU(x, h) -------------

__global__ __launch_bounds__(256)
void grub_all(const float* x, float* h,
              const unsigned short* __restrict__ Wis, const float* __restrict__ bi,
              const unsigned short* __restrict__ Whs, const float* __restrict__ bh,
              float* outs)
{
    const int tid = threadIdx.x;
    const int wv = tid >> 6, l = tid & 63;
    const int r0 = blockIdx.x * 64 + wv * 16;
    const int lk = (l >> 4) * 8;
    int rowA = r0 + (l & 15);
    int rowc = rowA < NN ? rowA : NN - 1;

    bf16x8 ax[4], hx[4];
    {
        const float* bx = x + (size_t)rowc * 128 + lk;
        const float* bhp = h + (size_t)rowc * 128 + lk;
#pragma unroll
        for (int kc = 0; kc < 4; ++kc) {
            ax[kc] = pack8(*(const float4*)(bx + kc * 32), *(const float4*)(bx + kc * 32 + 4));
            hx[kc] = pack8(*(const float4*)(bhp + kc * 32), *(const float4*)(bhp + kc * 32 + 4));
        }
    }
    const int colbase = l & 15;
    const int rbase = r0 + (l >> 4) * 4;

#pragma unroll
    for (int cg = 0; cg < 8; ++cg) {
        f32x4 air = {0.f,0.f,0.f,0.f}, ahr = {0.f,0.f,0.f,0.f};
        f32x4 aiz = {0.f,0.f,0.f,0.f}, ahz = {0.f,0.f,0.f,0.f};
        f32x4 ain = {0.f,0.f,0.f,0.f}, ahn = {0.f,0.f,0.f,0.f};
#pragma unroll
        for (int kc = 0; kc < 4; ++kc) {
            uint4 br = *(const uint4*)(Wis + ((size_t)(kc * 24 + 0 + cg) * 64 + l) * 8);
            uint4 hr = *(const uint4*)(Whs + ((size_t)(kc * 24 + 0 + cg) * 64 + l) * 8);
            uint4 bz = *(const uint4*)(Wis + ((size_t)(kc * 24 + 8 + cg) * 64 + l) * 8);
            uint4 hz = *(const uint4*)(Whs + ((size_t)(kc * 24 + 8 + cg) * 64 + l) * 8);
            uint4 bn = *(const uint4*)(Wis + ((size_t)(kc * 24 + 16 + cg) * 64 + l) * 8);
            uint4 hn = *(const uint4*)(Whs + ((size_t)(kc * 24 + 16 + cg) * 64 + l) * 8);
            air = __builtin_amdgcn_mfma_f32_16x16x32_bf16(ax[kc], *(bf16x8*)&br, air, 0, 0, 0);
            ahr = __builtin_amdgcn_mfma_f32_16x16x32_bf16(hx[kc], *(bf16x8*)&hr, ahr, 0, 0, 0);
            aiz = __builtin_amdgcn_mfma_f32_16x16x32_bf16(ax[kc], *(bf16x8*)&bz, aiz, 0, 0, 0);
            ahz = __builtin_amdgcn_mfma_f32_16x16x32_bf16(hx[kc], *(bf16x8*)&hz, ahz, 0, 0, 0);
            ain = __builtin_amdgcn_mfma_f32_16x16x32_bf16(ax[kc], *(bf16x8*)&bn, ain, 0, 0, 0);
            ahn = __builtin_amdgcn_mfma_f32_16x16x32_bf16(hx[kc], *(bf16x8*)&hn, ahn, 0, 0, 0);
        }
        int col = cg * 16 + colbase;
        float bir = bi[col],       bhr = bh[col];
        float biz = bi[128 + col], bhz = bh[128 + col];
        float bin = bi[256 + col], bhn = bh[256 + col];
#pragma unroll
        for (int j = 0; j < 4; ++j) {
            int gr = rbase + j;
            if (gr >= NN) continue;
            float r_ = 1.f / (1.f + __expf(-(air[j] + bir + ahr[j] + bhr)));
            float z_ = 1.f / (1.f + __expf(-(aiz[j] + biz + ahz[j] + bhz)));
            float n_ = tanhf(ain[j] + bin + r_ * (ahn[j] + bhn));
            float hv = h[(size_t)gr * 128 + col];
            float o = (1.f - z_) * n_ + z_ * hv;
            h[(size_t)gr * 128 + col] = o;
            outs[(size_t)gr * 128 + col] = o;
        }
    }
}

// ---------------- MFMA classifier: out = relu(Z @ cW1 + cb1) . cW2 + cb2 -----

__global__ __launch_bounds__(256)
void cls_mfma(const float* __restrict__ in,             // (N,384) fp32
              const unsigned short* __restrict__ Ws,    // swizzled cW1 (3 slices)
              const float* __restrict__ b1_,            // (128)
              const float* __restrict__ w2,             // (128)
              const float* __restrict__ b2_,            // (1)
              float* __restrict__ outv, int rows)
{
    const int tid = threadIdx.x;
    const int wv = tid >> 6, l = tid & 63;
    const int r0 = blockIdx.x * 64 + wv * 16;
    const int lk = (l >> 4) * 8;
    int rowA = r0 + (l & 15);
    int rowc = rowA < rows ? rowA : rows - 1;

    bf16x8 a[12];
    {
        const float* inf = in + (size_t)rowc * 384 + lk;
#pragma unroll
        for (int kc = 0; kc < 12; ++kc) {
            float4 u0 = *(const float4*)(inf + kc * 32);
            float4 u1 = *(const float4*)(inf + kc * 32 + 4);
            a[kc] = pack8(u0, u1);
        }
    }
    const int colbase = l & 15;
    const int rbase = r0 + (l >> 4) * 4;
    float part[4] = {0.f, 0.f, 0.f, 0.f};

#pragma unroll
    for (int cg = 0; cg < 8; ++cg) {
        f32x4 acc = {0.f, 0.f, 0.f, 0.f};
#pragma unroll
        for (int kc = 0; kc < 12; ++kc) {
            uint4 bu = *(const uint4*)(Ws + ((size_t)(kc * 8 + cg) * 64 + l) * 8);
            acc = __builtin_amdgcn_mfma_f32_16x16x32_bf16(a[kc], *(bf16x8*)&bu, acc, 0, 0, 0);
        }
        int col = cg * 16 + colbase;
        float b1v = b1_[col];
        float w2v = w2[col];
#pragma unroll
        for (int j = 0; j < 4; ++j)
            part[j] += fmaxf(acc[j] + b1v, 0.f) * w2v;
    }
    const float cb2v = b2_[0];
#pragma unroll
    for (int j = 0; j < 4; ++j) {
#pragma unroll
        for (int m = 1; m < 16; m <<= 1) part[j] += __shfl_xor(part[j], m);
        int gr = rbase + j;
        if ((l & 15) == 0 && gr < rows) outv[gr] = part[j] + cb2v;
    }
}

// ---------------- fused rel-attn + relu + residual + LayerNorm ----------------

__device__ inline float wred(float v)
{
#pragma unroll
    for (int m = 32; m; m >>= 1) v += __shfl_xor(v, m);
    return v;
}

__global__ __launch_bounds__(256)
void attnln_kernel(const unsigned short* __restrict__ agg16, // (R,N,128) bf16
                   const unsigned short* hin16,              // (N,128) bf16, may alias hout16
                   const float* __restrict__ q,
                   const float* __restrict__ g,
                   const float* __restrict__ b,
                   float* hout,                              // optional fp32
                   unsigned short* hout16)                   // optional bf16
{
    int wid = (blockIdx.x * 256 + threadIdx.x) >> 6;
    int lane = threadIdx.x & 63;
    if (wid >= NN) return;
    int n = wid;
    float2 qv = *(const float2*)(q + lane * 2);
    float sx[3], sy[3], sc[3];
#pragma unroll
    for (int r = 0; r < 3; ++r) {
        unsigned int v = *(const unsigned int*)(agg16 + ((size_t)r * NN + n) * 128 + lane * 2);
        sx[r] = b2f((unsigned short)(v & 0xffffu));
        sy[r] = b2f((unsigned short)(v >> 16));
        sc[r] = wred(tanhf(sx[r]) * qv.x + tanhf(sy[r]) * qv.y);
    }
    float mx = fmaxf(sc[0], fmaxf(sc[1], sc[2]));
    float e0 = __expf(sc[0] - mx), e1 = __expf(sc[1] - mx), e2 = __expf(sc[2] - mx);
    float isum = 1.f / (e0 + e1 + e2);
    float axv = (e0 * sx[0] + e1 * sx[1] + e2 * sx[2]) * isum;
    float ayv = (e0 * sy[0] + e1 * sy[1] + e2 * sy[2]) * isum;
    unsigned int hv = *(const unsigned int*)(hin16 + (size_t)n * 128 + lane * 2);
    float ux = b2f((unsigned short)(hv & 0xffffu)) + fmaxf(axv, 0.f);
    float uy = b2f((unsigned short)(hv >> 16)) + fmaxf(ayv, 0.f);
    float mean = wred(ux + uy) * (1.f / 128.f);
    float dx = ux - mean, dy = uy - mean;
    float var = wred(dx * dx + dy * dy) * (1.f / 128.f);
    float rstd = rsqrtf(var + 1e-5f);
    float2 gv = *(const float2*)(g + lane * 2);
    float2 bv = *(const float2*)(b + lane * 2);
    float ox = dx * rstd * gv.x + bv.x;
    float oy = dy * rstd * gv.y + bv.y;
    if (hout) {
        float2 o; o.x = ox; o.y = oy;
        *(float2*)(hout + (size_t)n * 128 + lane * 2) = o;
    }
    if (hout16) {
        unsigned int p = (unsigned int)f2b(ox) | ((unsigned int)f2b(oy) << 16);
        *(unsigned int*)(hout16 + (size_t)n * 128 + lane * 2) = p;
    }
}

// ---------------- temporal attention (also emits `last`) ----------------

__global__ __launch_bounds__(256)
void temporal_kernel(const float* __restrict__ outs, // (T,N,128)
                     const float* __restrict__ tq,
                     float* __restrict__ zbuf)       // (N,384)
{
    int wid = (blockIdx.x * 256 + threadIdx.x) >> 6;
    int lane = threadIdx.x & 63;
    if (wid >= NN) return;
    int n = wid;
    float2 qv = *(const float2*)(tq + lane * 2);
    float2 o[4];
    float sc[4];
#pragma unroll
    for (int t = 0; t < 4; ++t) {
        o[t] = *(const float2*)(outs + ((size_t)t * NN + n) * 128 + lane * 2);
        sc[t] = wred(tanhf(o[t].x) * qv.x + tanhf(o[t].y) * qv.y);
    }
    float mx = fmaxf(fmaxf(sc[0], sc[1]), fmaxf(sc[2], sc[3]));
    float e[4];
    float sum = 0.f;
#pragma unroll
    for (int t = 0; t < 4; ++t) { e[t] = __expf(sc[t] - mx); sum += e[t]; }
    float isum = 1.f / sum;
    float axv = 0.f, ayv = 0.f;
#pragma unroll
    for (int t = 0; t < 4; ++t) { axv += e[t] * o[t].x; ayv += e[t] * o[t].y; }
    axv *= isum; ayv *= isum;
    float* zr = zbuf + (size_t)n * 384;
    *(float2*)(zr + lane * 2) = o[3];
    float2 at; at.x = axv; at.y = ayv;
    *(float2*)(zr + 128 + lane * 2) = at;
}

// ---------------- launch ----------------

extern "C" void kernel_launch(void* const* d_in, const int* in_sizes, int n_in,
                              void* d_out, int out_size, void* d_ws, size_t ws_size,
                              hipStream_t stream)
{
    const float* feat = (const float*)d_in[0];
    const int* srcp   = (const int*)d_in[1];
    const int* dstp   = (const int*)d_in[2];
    const float* ewp  = (const float*)d_in[3];
    const float* W_in = (const float*)d_in[4];
    const float* b_in = (const float*)d_in[5];
    const float* W1   = (const float*)d_in[6];
    const float* b1   = (const float*)d_in[7];
    const float* W2   = (const float*)d_in[8];
    const float* b2   = (const float*)d_in[9];
    const float* q1   = (const float*)d_in[10];
    const float* q2   = (const float*)d_in[11];
    const float* ln1g = (const float*)d_in[12];
    const float* ln1b = (const float*)d_in[13];
    const float* ln2g = (const float*)d_in[14];
    const float* ln2b = (const float*)d_in[15];
    const float* gWih = (const float*)d_in[16];
    const float* gbih = (const float*)d_in[17];
    const float* gWhh = (const float*)d_in[18];
    const float* gbhh = (const float*)d_in[19];
    const float* tq   = (const float*)d_in[20];
    const float* tW1  = (const float*)d_in[21];
    const float* tb1  = (const float*)d_in[22];
    const float* tW2  = (const float*)d_in[23];
    const float* tb2  = (const float*)d_in[24];
    const float* cW1  = (const float*)d_in[25];
    const float* cb1  = (const float*)d_in[26];
    const float* cW2  = (const float*)d_in[27];
    const float* cb2  = (const float*)d_in[28];
    float* outv = (float*)d_out;
    (void)in_sizes; (void)n_in; (void)out_size;

    // ---- ws layout (bytes), peak ~205.4 MB ----
    // o_POOL overlay discipline:
    //   phase A: AGG16 / H16 / SRCW / ROWS / CURS          (all dead after phase A,
    //            except ROWS/CURS/SRCW reused per-t inside phase A)
    //   phase C: ZB spans o_POOL..o_POOL+76.8M  -> NOTHING else may live there.
    //            tab bf16 scratch goes to o_H (HST region, dead after phase B).
    const size_t o_HS    = 0;                      // (T,N,128) fp32 = 102,400,000
    const size_t o_POOL  = 102400000;
    const size_t o_AGG16 = o_POOL;                 // phase A: (R,N,128) bf16 = 38.4 MB
    const size_t o_H16   = o_POOL + 38400000;      // phase A: (N,128) bf16 = 12.8 MB
    const size_t o_SRCW  = o_POOL + 51200000;      // phase A: (R,E) int2 = 12 MB
    const size_t o_ROWS  = o_POOL + 63200000;      // (12,N+1) int -> pad
    const size_t o_CURS  = o_POOL + 65600128;      // (12,N) int -> pad
    const size_t o_ZB    = o_POOL;                 // phase C: (N,384) fp32 = 76.8 MB
    const size_t o_H     = o_POOL + 76800000;      // (N,128) fp32 = 25.6 MB (HST / TAB16)
    const size_t o_WSZ   = o_H + 25600000;         // swizzled bf16 weights
    const size_t NEED    = o_WSZ + 589824;

    if (ws_size < NEED) {
        diag_kernel<<<dim3((NN + 255) / 256), dim3(256), 0, stream>>>(outv, (float)(ws_size >> 20));
        return;
    }

    char* wsb = (char*)d_ws;
    float* HS             = (float*)(wsb + o_HS);
    unsigned short* AGG16 = (unsigned short*)(wsb + o_AGG16);
    unsigned short* H16   = (unsigned short*)(wsb + o_H16);
    int2*  SRCW           = (int2*)(wsb + o_SRCW);
    int*   ROWS           = (int*)(wsb + o_ROWS);
    int*   CURS           = (int*)(wsb + o_CURS);
    float* ZB             = (float*)(wsb + o_ZB);
    float* HST            = (float*)(wsb + o_H);
    unsigned short* TAB16 = (unsigned short*)(wsb + o_H);   // phase C tab scratch (outside ZB!)
    unsigned short* WSZ   = (unsigned short*)(wsb + o_WSZ);

    unsigned short* Wins  = WSZ;            // 16384
    unsigned short* W1s   = WSZ + 16384;    // 49152
    unsigned short* W2s   = WSZ + 65536;    // 49152
    unsigned short* gWihs = WSZ + 114688;   // 49152
    unsigned short* gWhhs = WSZ + 163840;   // 49152
    unsigned short* tW1s  = WSZ + 212992;   // 16384
    unsigned short* tW2s  = WSZ + 229376;   // 16384
    unsigned short* cW1s  = WSZ + 245760;   // 49152

    const dim3 blk(256);
    const int G64 = (NN + 63) / 64;
    const dim3 gE((EE + 255) / 256, RR);
    const dim3 gEall((EE + 255) / 256, TT * RR);

    // ---------- weight swizzle ----------
    wswz_kernel<<<dim3((1 * 16384 + 255) / 256), blk, 0, stream>>>(W_in, Wins, 128, 1);
    wswz_kernel<<<dim3((3 * 16384 + 255) / 256), blk, 0, stream>>>(W1,   W1s,  128, 3);
    wswz_kernel<<<dim3((3 * 16384 + 255) / 256), blk, 0, stream>>>(W2,   W2s,  128, 3);
    wswz_kernel<<<dim3((1 * 49152 + 255) / 256), blk, 0, stream>>>(gWih, gWihs, 384, 1);
    wswz_kernel<<<dim3((1 * 49152 + 255) / 256), blk, 0, stream>>>(gWhh, gWhhs, 384, 1);
    wswz_kernel<<<dim3((1 * 16384 + 255) / 256), blk, 0, stream>>>(tW1,  tW1s, 128, 1);
    wswz_kernel<<<dim3((1 * 16384 + 255) / 256), blk, 0, stream>>>(tW2,  tW2s, 128, 1);
    wswz_kernel<<<dim3((3 * 16384 + 255) / 256), blk, 0, stream>>>(cW1,  cW1s, 128, 3);

    // ---------- CSR count/scan for all 12 graphs (hoisted) ----------
    hipMemsetAsync(CURS, 0, (size_t)TT * RR * NN * 4, stream);
    count_kernel<<<gEall, blk, 0, stream>>>(dstp, CURS);
    scan_kernel<<<dim3(TT * RR), dim3(1024), 0, stream>>>(CURS, ROWS);

    // ---------- phase A: spatial layers, t-outer ----------
    for (int t = 0; t < TT; ++t) {
        const size_t eoff = (size_t)t * RR * EE;
        fill_kernel<<<gE, blk, 0, stream>>>(srcp + eoff, dstp + eoff, ewp + eoff,
                                            CURS + (size_t)t * RR * NN, SRCW);

        // h0 = relu(feat[t] @ W_in + b_in) -> H16 (bf16 only)
        mmb<<<dim3(G64, 1, 1), blk, 0, stream>>>(
            (const void*)(feat + (size_t)t * NN * 128), 0, 0, 128,
            Wins, 0, b_in, 0, (float*)0, 0, 0, H16, 0, NN, 1);

        for (int layer = 0; layer < 2; ++layer) {
            const unsigned short* Wls = layer ? W2s : W1s;
            const float* bl = layer ? b2 : b1;
            const float* ql = layer ? q2 : q1;
            const float* lg = layer ? ln2g : ln1g;
            const float* lb = layer ? ln2b : ln1b;
            float* hout = layer ? (HS + (size_t)t * NN * 128) : (float*)0;
            unsigned short* hout16 = layer ? (unsigned short*)0 : H16;

            agg16_kernel<<<dim3((RR * NN) / 4), blk, 0, stream>>>(
                H16, SRCW, ROWS + (size_t)t * RR * (NN + 1), AGG16);
            mmb<<<dim3(G64, 1, RR), blk, 0, stream>>>(
                (const void*)AGG16, 1, (long)NN * 128, 128,
                Wls, 16384, bl, 128, (float*)0, 0, 0, AGG16, (long)NN * 128, NN, 0);
            attnln_kernel<<<dim3(NN / 4), blk, 0, stream>>>(
                AGG16, H16, ql, lg, lb, hout, hout16);
        }
    }

    // ---------- phase B: fused GRU over T (outs alias HS[t]) ----------
    hipMemsetAsync(HST, 0, (size_t)NN * 128 * 4, stream);
    for (int t = 0; t < TT; ++t) {
        float* xt = HS + (size_t)t * NN * 128;
        grub_all<<<dim3(G64), blk, 0, stream>>>(xt, HST, gWihs, gbih, gWhhs, gbhh, xt);
    }

    // ---------- phase C: temporal attn + tab + classifier ----------
    temporal_kernel<<<dim3(NN / 4), blk, 0, stream>>>(HS, tq, ZB);

    // tab stage 1: relu(feat[3] @ tW1 + tb1) -> TAB16 (o_H region, NOT inside ZB)
    mmb<<<dim3(G64, 1, 1), blk, 0, stream>>>(
        (const void*)(feat + (size_t)3 * NN * 128), 0, 0, 128,
        tW1s, 0, tb1, 0, (float*)0, 0, 0, TAB16, 0, NN, 1);
    // tab stage 2: relu(TAB16 @ tW2 + tb2) -> ZB cols 256:384
    mmb<<<dim3(G64, 1, 1), blk, 0, stream>>>(
        (const void*)TAB16, 1, 0, 128,
        tW2s, 0, tb2, 0, ZB + 256, 0, 384, (unsigned short*)0, 0, NN, 1);

    cls_mfma<<<dim3(G64), blk, 0, stream>>>(ZB, cW1s, cb1, cW2, cb2, outv, NN);
}